// Round 13
// baseline (811.470 us; speedup 1.0000x reference)
//
#include <hip/hip_runtime.h>
#include <cstdint>
#include <cstddef>

// ---------------------------------------------------------------------------
// SSLModel: dual-branch GCN + global max pool + MLP head.
// Round 13: remove the forced lgkmcnt(0)+barrier BETWEEN ds_reads and MFMA in
// both mgemm kernels (it drained all 24 LDS reads before the first MFMA; the
// compiler's fine-grained lgkmcnt lets MFMA start as operands land — m97
// pattern). Barrier moves after the MFMA cluster (that's where the overwrite
// hazard is). Counted vmcnt(8) staging unchanged. Rest identical to R12.
// ---------------------------------------------------------------------------

#define NN 10000      // nodes per graph-batch
#define NNP2 10240    // padded to 256 (40 tiles)
#define MT2 20480     // 2*NNP2 merged rows
#define NB2 640       // MT2/32 node-blocks
#define NE 160000     // edges per branch
#define NG 128        // graphs per branch

typedef short bf16x8 __attribute__((ext_vector_type(8)));
typedef float f32x4 __attribute__((ext_vector_type(4)));

__device__ __forceinline__ unsigned short f2bf(float x) {
  unsigned u = __float_as_uint(x);
  u += 0x7FFFu + ((u >> 16) & 1u);   // RNE (finite inputs)
  return (unsigned short)(u >> 16);
}
__device__ __forceinline__ float bf2f(unsigned short h) {
  return __uint_as_float(((unsigned)h) << 16);
}
__device__ __forceinline__ void fma4(float4& d, float s, const float4& u) {
  d.x = fmaf(s, u.x, d.x);
  d.y = fmaf(s, u.y, d.y);
  d.z = fmaf(s, u.z, d.z);
  d.w = fmaf(s, u.w, d.w);
}

#define GLOAD_LDS16(gp, lp)                                                  \
  __builtin_amdgcn_global_load_lds(                                          \
      (const __attribute__((address_space(1))) void*)(gp),                   \
      (__attribute__((address_space(3))) void*)(lp), 16, 0, 0)

// ---------------- CSR build (both branches batched) ----------------

__global__ void k_count2(const int* __restrict__ eis, const int* __restrict__ eit,
                         int* __restrict__ cnt) {
  int i = blockIdx.x * blockDim.x + threadIdx.x;
  if (i >= 2 * NE) return;
  int d;
  if (i < NE) d = eis[NE + i];
  else        d = eit[NE + (i - NE)] + NNP2;
  atomicAdd(&cnt[d], 1);
}

// scan + dinv (single block, 256 thr, n = MT2)
__global__ void k_scan(const int* __restrict__ cnt, int* __restrict__ row_ptr,
                       int* __restrict__ cursor, float* __restrict__ dinv) {
  __shared__ int part[256];
  __shared__ int partex[257];
  int t = threadIdx.x;
  const int n = MT2;
  const int CH = n / 256;
  int base = t * CH;
  int s = 0;
  for (int i = 0; i < CH; ++i) s += cnt[base + i];
  part[t] = s;
  __syncthreads();
  if (t == 0) {
    int acc = 0;
    for (int i = 0; i < 256; ++i) { partex[i] = acc; acc += part[i]; }
    partex[256] = acc;
  }
  __syncthreads();
  int acc = partex[t];
  for (int i = 0; i < CH; ++i) {
    int idx = base + i;
    row_ptr[idx] = acc;
    cursor[idx]  = acc;
    dinv[idx] = rsqrtf((float)cnt[idx] + 1.0f);
    acc += cnt[idx];
  }
  if (t == 255) row_ptr[n] = partex[256];
}

// src-only CSR (weight recomputed in agg), grouped by dst_global
__global__ void k_scatter2(const int* __restrict__ eis, const int* __restrict__ eit,
                           int* __restrict__ cursor, int* __restrict__ csr_src) {
  int i = blockIdx.x * blockDim.x + threadIdx.x;
  if (i >= 2 * NE) return;
  int s, d;
  if (i < NE) { s = eis[i]; d = eis[NE + i]; }
  else { int j = i - NE; s = eit[j] + NNP2; d = eit[NE + j] + NNP2; }
  int pos = atomicAdd(&cursor[d], 1);
  csr_src[pos] = s;
}

// ---------------- XCD-pinned chunk-column aggregate + bf16 split -----------
template <int NCH, bool DUAL>
__global__ __launch_bounds__(256) void k_agg_x(
    const float* __restrict__ in0, const float* __restrict__ in1,
    unsigned short* __restrict__ Ah, unsigned short* __restrict__ Al,
    const int* __restrict__ row_ptr, const int* __restrict__ csr_src,
    const float* __restrict__ dinv) {
  constexpr int F4TOT = NCH * 8;
  const int bid = blockIdx.x;
  const int xcd = bid & 7;
  const int seq = bid >> 3;
  int chunk, nodeblk;
  if constexpr (NCH >= 8) {
    int phase = seq / NB2;
    nodeblk = seq - phase * NB2;
    chunk = phase * 8 + xcd;
  } else {  // NCH == 4: two XCDs share a chunk (even/odd node-blocks)
    chunk = xcd >> 1;
    nodeblk = (seq << 1) | (xcd & 1);
  }
  const int t = threadIdx.x;
  const int node = nodeblk * 32 + (t >> 3);
  const int f4 = chunk * 8 + (t & 7);

  size_t o = (size_t)node * F4TOT + f4;
  ushort4* oh = (ushort4*)Ah + o;
  ushort4* ol = (ushort4*)Al + o;
  int local = (node < NNP2) ? node : (node - NNP2);
  if (local >= NN) {   // pad row
    *oh = make_ushort4(0, 0, 0, 0);
    *ol = make_ushort4(0, 0, 0, 0);
    return;
  }
  const float4* i0 = (const float4*)in0;
  const float4* i1 = (const float4*)in1;
  auto rowp = [&](int g) -> const float4* {
    if (DUAL)
      return (g < NNP2) ? (i0 + (size_t)g * F4TOT)
                        : (i1 + (size_t)(g - NNP2) * F4TOT);
    return i0 + (size_t)g * F4TOT;
  };

  float di = dinv[node];
  float sw = di * di;
  float4 v = rowp(node)[f4];
  float4 acc;
  acc.x = sw * v.x; acc.y = sw * v.y; acc.z = sw * v.z; acc.w = sw * v.w;

  const int e0 = row_ptr[node], e1 = row_ptr[node + 1];
  int e = e0;
  for (; e + 4 <= e1; e += 4) {
    int s0 = csr_src[e], s1 = csr_src[e + 1];
    int s2 = csr_src[e + 2], s3 = csr_src[e + 3];
    float4 u0 = rowp(s0)[f4];
    float4 u1 = rowp(s1)[f4];
    float4 u2 = rowp(s2)[f4];
    float4 u3 = rowp(s3)[f4];
    float w0 = dinv[s0] * di, w1 = dinv[s1] * di;
    float w2 = dinv[s2] * di, w3 = dinv[s3] * di;
    fma4(acc, w0, u0);
    fma4(acc, w1, u1);
    fma4(acc, w2, u2);
    fma4(acc, w3, u3);
  }
  for (; e < e1; ++e) {
    int s = csr_src[e];
    float4 u = rowp(s)[f4];
    fma4(acc, dinv[s] * di, u);
  }

  ushort4 h, l;
  h.x = f2bf(acc.x); l.x = f2bf(acc.x - bf2f(h.x));
  h.y = f2bf(acc.y); l.y = f2bf(acc.y - bf2f(h.y));
  h.z = f2bf(acc.z); l.z = f2bf(acc.z - bf2f(h.z));
  h.w = f2bf(acc.w); l.w = f2bf(acc.w - bf2f(h.w));
  *oh = h;
  *ol = l;
}

// ---------------- weight transpose + split, 2 weight sets batched --------
__global__ __launch_bounds__(256) void k_wsplit2(
    const float* __restrict__ W0, unsigned short* __restrict__ H0,
    unsigned short* __restrict__ L0,
    const float* __restrict__ W1, unsigned short* __restrict__ H1,
    unsigned short* __restrict__ L1, int K, int N) {
  const float* W = blockIdx.z ? W1 : W0;
  unsigned short* Ht = blockIdx.z ? H1 : H0;
  unsigned short* Lt = blockIdx.z ? L1 : L0;
  __shared__ float tile[32][33];
  int nb = blockIdx.x * 32, kb = blockIdx.y * 32;
  int tx = threadIdx.x & 31, ty = threadIdx.x >> 5;
#pragma unroll
  for (int r = ty; r < 32; r += 8)
    tile[r][tx] = W[(size_t)(kb + r) * N + nb + tx];
  __syncthreads();
#pragma unroll
  for (int r = ty; r < 32; r += 8) {
    float x = tile[tx][r];  // = W[kb+tx][nb+r]
    unsigned short h = f2bf(x);
    unsigned short lo = f2bf(x - bf2f(h));
    size_t o = (size_t)(nb + r) * K + kb + tx;
    Ht[o] = h;
    Lt[o] = lo;
  }
}

// ---------------- split-bf16 MFMA GEMM 128x128 ----------------------------
// Schedule per K-step: STAGE(next) ; vmcnt(8) ; s_barrier ; ds_reads ;
// MFMA (compiler fine-grained lgkm waits) ; lgkmcnt(0) [free, compiler
// fence] ; s_barrier. MFMA starts as soon as first frags land.
template <bool RELU, int GX>
__global__ __launch_bounds__(256) void k_mgemm(
    const unsigned short* __restrict__ Ah, const unsigned short* __restrict__ Al,
    const unsigned short* __restrict__ Bh_a, const unsigned short* __restrict__ Bl_a,
    const unsigned short* __restrict__ Bh_b, const unsigned short* __restrict__ Bl_b,
    const float* __restrict__ bias_a, const float* __restrict__ bias_b,
    float* __restrict__ C, int N, int K) {
  __shared__ char smem[65536];  // 2 x [Ah|Al|Bh|Bl] x 8KiB
  const int t = threadIdx.x;
  const int w = t >> 6, l = t & 63;

  const int bid = blockIdx.x;
  const int bn_ = bid & (GX - 1), bm_ = bid / GX;
  const int bm = bm_ * 128, bn = bn_ * 128;
  const bool sec = bm >= NNP2;
  const unsigned short* Bh = sec ? Bh_b : Bh_a;
  const unsigned short* Bl = sec ? Bl_b : Bl_a;
  const float* bias = sec ? bias_b : bias_a;

  const int wr = w >> 1, wc = w & 1;

  f32x4 acc[4][4] = {};

  // staging: wave w owns matrix w entirely (8 x 1KiB chunks)
  const unsigned short* g0 = (w == 0) ? Ah : (w == 1) ? Al : (w == 2) ? Bh : Bl;
  const int rb = (w < 2) ? bm : bn;
  const unsigned short* gbase = g0 + (size_t)(rb + (l & 15)) * K + ((l >> 4) * 8);
  const int sdoff = w * 8192 + l * 16;
  const int saoff = wr * 4096 + l * 16;          // A-hi frags; A-lo at +8192
  const int sboff = 16384 + wc * 4096 + l * 16;  // B-hi frags; B-lo at +8192

  const int nt = K >> 5;

#define STAGE(kt, b)                                                         \
  {                                                                          \
    const unsigned short* gk = gbase + ((kt) << 5);                          \
    char* sd = smem + (b)*32768 + sdoff;                                     \
    _Pragma("unroll") for (int s = 0; s < 8; ++s)                            \
        GLOAD_LDS16(gk + (size_t)s * 16 * K, sd + s * 1024);                 \
  }

  STAGE(0, 0)

  for (int kt = 0; kt < nt; ++kt) {
    const int cur = kt & 1;
    if (kt + 1 < nt) {
      STAGE(kt + 1, cur ^ 1)
      asm volatile("s_waitcnt vmcnt(8)" ::: "memory");  // tile kt landed
    } else {
      asm volatile("s_waitcnt vmcnt(0)" ::: "memory");
    }
    __builtin_amdgcn_sched_barrier(0);
    __builtin_amdgcn_s_barrier();  // collective: buf[cur] fully staged

    const char* sA = smem + cur * 32768 + saoff;
    const char* sB = smem + cur * 32768 + sboff;
    bf16x8 a[4][2], b[4][2];
#pragma unroll
    for (int i = 0; i < 4; ++i) {
      a[i][0] = *(const bf16x8*)(sA + i * 1024);
      a[i][1] = *(const bf16x8*)(sA + 8192 + i * 1024);
    }
#pragma unroll
    for (int j = 0; j < 4; ++j) {
      b[j][0] = *(const bf16x8*)(sB + j * 1024);
      b[j][1] = *(const bf16x8*)(sB + 8192 + j * 1024);
    }
    __builtin_amdgcn_s_setprio(1);
#pragma unroll
    for (int i = 0; i < 4; ++i)
#pragma unroll
      for (int j = 0; j < 4; ++j) {
        acc[i][j] = __builtin_amdgcn_mfma_f32_16x16x32_bf16(a[i][0], b[j][0], acc[i][j], 0, 0, 0);
        acc[i][j] = __builtin_amdgcn_mfma_f32_16x16x32_bf16(a[i][0], b[j][1], acc[i][j], 0, 0, 0);
        acc[i][j] = __builtin_amdgcn_mfma_f32_16x16x32_bf16(a[i][1], b[j][0], acc[i][j], 0, 0, 0);
      }
    __builtin_amdgcn_s_setprio(0);
    asm volatile("s_waitcnt lgkmcnt(0)" ::: "memory");  // retired; fence
    __builtin_amdgcn_s_barrier();  // all reads done; next STAGE may overwrite
  }
#undef STAGE

  // epilogue: C/D layout: col = lane&15, row = (lane>>4)*4 + reg
  const int r0 = bm + wr * 64 + ((l >> 4) << 2);
  const int c0 = bn + wc * 64 + (l & 15);
#pragma unroll
  for (int j = 0; j < 4; ++j) {
    const int col = c0 + j * 16;
    const float bv = bias[col];
#pragma unroll
    for (int i = 0; i < 4; ++i) {
      const int row = r0 + i * 16;
#pragma unroll
      for (int r = 0; r < 4; ++r) {
        float v = acc[i][j][r] + bv;
        if (RELU) v = fmaxf(v, 0.f);
        C[(size_t)(row + r) * N + col] = v;
      }
    }
  }
}

// ---------------- L3: 256x256 / 8-wave mgemm + fused bias/ReLU/max-pool ----
// Same reordered schedule as k_mgemm (MFMA before the drain barrier).
__global__ __launch_bounds__(512, 2) void k_mgemm3(
    const unsigned short* __restrict__ Ah, const unsigned short* __restrict__ Al,
    const unsigned short* __restrict__ Bh_a, const unsigned short* __restrict__ Bl_a,
    const unsigned short* __restrict__ Bh_b, const unsigned short* __restrict__ Bl_b,
    const float* __restrict__ bias_a, const float* __restrict__ bias_b,
    const int* __restrict__ bs, const int* __restrict__ bt,
    float* __restrict__ P2, int N, int K) {
  __shared__ char smem[131072];
  const int t = threadIdx.x;
  const int w = t >> 6, l = t & 63;
  const int bid = blockIdx.x;
  const int bn_ = bid & 7, bm_ = bid >> 3;
  const int bm = bm_ * 256, bn = bn_ * 256;
  const bool sec = bm >= NNP2;            // 10240 % 256 == 0: no straddle
  const unsigned short* Bh = sec ? Bh_b : Bh_a;
  const unsigned short* Bl = sec ? Bl_b : Bl_a;
  const float* bias = sec ? bias_b : bias_a;
  const int* batch = sec ? bt : bs;
  float* P2g = P2 + (sec ? (size_t)NG * 2048 : 0);
  const int lbase = bm - (sec ? NNP2 : 0);  // branch-local row base

  const int wr = w >> 2, wc = w & 3;

  f32x4 acc[8][4] = {};

  // staging: part = w>>1 (0:Ahi 1:Alo 2:Bhi 3:Blo); half = w&1 (rows +0/+128)
  const int part = w >> 1, half = w & 1;
  const unsigned short* gmat = (part == 0) ? Ah : (part == 1) ? Al
                             : (part == 2) ? Bh : Bl;
  const int rb = ((part < 2) ? bm : bn) + half * 128;
  const unsigned short* gsbase = gmat + (size_t)(rb + (l & 15)) * K + ((l >> 4) * 8);
  const int sdoff = part * 16384 + half * 8192 + l * 16;

  const int saoff = (wr * 8) * 1024 + l * 16;          // A-hi; A-lo +16384
  const int sboff = 32768 + (wc * 4) * 1024 + l * 16;  // B-hi; B-lo +16384

  const int nt = K >> 5;

#define STAGE3(kt, b)                                                        \
  {                                                                          \
    _Pragma("unroll") for (int c = 0; c < 8; ++c)                            \
        GLOAD_LDS16(gsbase + (size_t)c * 16 * K + ((kt) << 5),               \
                    smem + (b)*65536 + sdoff + c * 1024);                    \
  }

  STAGE3(0, 0)

  for (int kt = 0; kt < nt; ++kt) {
    const int cur = kt & 1;
    if (kt + 1 < nt) {
      STAGE3(kt + 1, cur ^ 1)
      asm volatile("s_waitcnt vmcnt(8)" ::: "memory");
    } else {
      asm volatile("s_waitcnt vmcnt(0)" ::: "memory");
    }
    __builtin_amdgcn_sched_barrier(0);
    __builtin_amdgcn_s_barrier();

    const char* base = smem + cur * 65536;
    bf16x8 bh[4], blo[4], ah[8], alo[8];
#pragma unroll
    for (int j = 0; j < 4; ++j) {
      bh[j]  = *(const bf16x8*)(base + sboff + j * 1024);
      blo[j] = *(const bf16x8*)(base + sboff + 16384 + j * 1024);
    }
#pragma unroll
    for (int i = 0; i < 8; ++i) {
      ah[i]  = *(const bf16x8*)(base + saoff + i * 1024);
      alo[i] = *(const bf16x8*)(base + saoff + 16384 + i * 1024);
    }
    __builtin_amdgcn_s_setprio(1);
#pragma unroll
    for (int i = 0; i < 8; ++i)
#pragma unroll
      for (int j = 0; j < 4; ++j) {
        acc[i][j] = __builtin_amdgcn_mfma_f32_16x16x32_bf16(ah[i], bh[j], acc[i][j], 0, 0, 0);
        acc[i][j] = __builtin_amdgcn_mfma_f32_16x16x32_bf16(ah[i], blo[j], acc[i][j], 0, 0, 0);
        acc[i][j] = __builtin_amdgcn_mfma_f32_16x16x32_bf16(alo[i], bh[j], acc[i][j], 0, 0, 0);
      }
    __builtin_amdgcn_s_setprio(0);
    asm volatile("s_waitcnt lgkmcnt(0)" ::: "memory");  // retired; fence
    __builtin_amdgcn_s_barrier();
  }
#undef STAGE3

  // epilogue: bias + ReLU + segmented atomicMax pool (no C store)
  const int r0l = lbase + wr * 128 + ((l >> 4) << 2);
  const int c0 = bn + wc * 64 + (l & 15);
#pragma unroll
  for (int j = 0; j < 4; ++j) {
    const int col = c0 + j * 16;
    const float bv = bias[col];
    float* Pcol = P2g + col;
#pragma unroll
    for (int i = 0; i < 8; ++i) {
      const int rl = r0l + i * 16;
      if (rl >= NN) continue;
      float v0 = fmaxf(acc[i][j][0] + bv, 0.f);
      float v1 = fmaxf(acc[i][j][1] + bv, 0.f);
      float v2 = fmaxf(acc[i][j][2] + bv, 0.f);
      float v3 = fmaxf(acc[i][j][3] + bv, 0.f);
      if (rl + 3 < NN) {
        int g0 = batch[rl], g3 = batch[rl + 3];
        if (g0 == g3) {
          float m = fmaxf(fmaxf(v0, v1), fmaxf(v2, v3));
          atomicMax((int*)(Pcol + (size_t)g0 * 2048), __float_as_int(m));
        } else {
          int g1 = batch[rl + 1], g2 = batch[rl + 2];
          atomicMax((int*)(Pcol + (size_t)g0 * 2048), __float_as_int(v0));
          atomicMax((int*)(Pcol + (size_t)g1 * 2048), __float_as_int(v1));
          atomicMax((int*)(Pcol + (size_t)g2 * 2048), __float_as_int(v2));
          atomicMax((int*)(Pcol + (size_t)g3 * 2048), __float_as_int(v3));
        }
      } else {
        float vv[4] = {v0, v1, v2, v3};
        for (int r = 0; r < 4; ++r) {
          if (rl + r < NN) {
            int g = batch[rl + r];
            atomicMax((int*)(Pcol + (size_t)g * 2048), __float_as_int(vv[r]));
          }
        }
      }
    }
  }
}

// ---------------- split-K fp32 GEMM for the tiny head (M=128) -------------
__global__ __launch_bounds__(256) void k_gemm_sk(
    const float* __restrict__ A, const float* __restrict__ A2,
    const float* __restrict__ B,
    float* __restrict__ PART, int M, int N, int K, int KS) {
  __shared__ float As[32][64];
  __shared__ float Bs[32][64];

  int t = threadIdx.x;
  int tx = t & 15, ty = t >> 4;
  int bm = blockIdx.y * 64, bn = blockIdx.x * 64;
  int kbeg = blockIdx.z * KS, kend = kbeg + KS;

  float acc[4][4] = {};

  int arow0 = t >> 3;
  int ak4 = (t & 7) * 4;
  int brow0 = t >> 4;
  int bn4 = (t & 15) * 4;
  const bool n4al = (N & 3) == 0;

  for (int k0 = kbeg; k0 < kend; k0 += 32) {
#pragma unroll
    for (int c = 0; c < 2; ++c) {
      int row = arow0 + c * 32;
      int gr = bm + row;
      float4 v = make_float4(0.f, 0.f, 0.f, 0.f);
      if (gr < M) {
        v = *(const float4*)&A[(size_t)gr * K + k0 + ak4];
        if (A2) {
          float4 v2 = *(const float4*)&A2[(size_t)gr * K + k0 + ak4];
          v.x += v2.x; v.y += v2.y; v.z += v2.z; v.w += v2.w;
        }
      }
      As[ak4 + 0][row] = v.x;
      As[ak4 + 1][row] = v.y;
      As[ak4 + 2][row] = v.z;
      As[ak4 + 3][row] = v.w;
    }
#pragma unroll
    for (int c = 0; c < 2; ++c) {
      int row = brow0 + c * 16;
      int gc = bn + bn4;
      const float* bp = &B[(size_t)(k0 + row) * N + gc];
      float4 v;
      if (n4al && gc + 3 < N) {
        v = *(const float4*)bp;
      } else {
        v = make_float4(0.f, 0.f, 0.f, 0.f);
        if (gc < N) v.x = bp[0];
        if (gc + 1 < N) v.y = bp[1];
        if (gc + 2 < N) v.z = bp[2];
        if (gc + 3 < N) v.w = bp[3];
      }
      *(float4*)&Bs[row][bn4] = v;
    }
    __syncthreads();

#pragma unroll
    for (int kk = 0; kk < 32; ++kk) {
      float4 a = *(const float4*)&As[kk][ty * 4];
      float4 b = *(const float4*)&Bs[kk][tx * 4];
      float av[4] = {a.x, a.y, a.z, a.w};
      float bv[4] = {b.x, b.y, b.z, b.w};
#pragma unroll
      for (int i = 0; i < 4; ++i)
#pragma unroll
        for (int j = 0; j < 4; ++j)
          acc[i][j] = fmaf(av[i], bv[j], acc[i][j]);
    }
    __syncthreads();
  }

  float* P = PART + (size_t)blockIdx.z * M * N;
  int r0 = bm + ty * 4, c0 = bn + tx * 4;
#pragma unroll
  for (int i = 0; i < 4; ++i) {
    int r = r0 + i;
    if (r < M) {
#pragma unroll
      for (int j = 0; j < 4; ++j) {
        int c = c0 + j;
        if (c < N) P[(size_t)r * N + c] = acc[i][j];
      }
    }
  }
}

// reduce SK partials + bias (+relu or logits+sigmoid)
template <bool SIG>
__global__ void k_reduce(const float* __restrict__ PART,
                         const float* __restrict__ bias,
                         float* __restrict__ C, float* __restrict__ C2,
                         int MN, int N, int SK) {
  int i = blockIdx.x * blockDim.x + threadIdx.x;
  if (i >= MN) return;
  float s = 0.f;
  for (int z = 0; z < SK; ++z) s += PART[(size_t)z * MN + i];
  s += bias[i % N];
  if (SIG) {
    C[i] = s;
    C2[i] = 1.0f / (1.0f + __expf(-s));
  } else {
    C[i] = fmaxf(s, 0.f);
  }
}

// ---------------- entry ----------------

extern "C" void kernel_launch(void* const* d_in, const int* in_sizes, int n_in,
                              void* d_out, int out_size, void* d_ws, size_t ws_size,
                              hipStream_t stream) {
  const float* x_s = (const float*)d_in[0];
  const float* x_t = (const float*)d_in[1];
  const int* ei_s = (const int*)d_in[2];
  const int* ei_t = (const int*)d_in[3];
  const int* xs_batch = (const int*)d_in[4];
  const int* xt_batch = (const int*)d_in[5];
  const float* W_enc1 = (const float*)d_in[6];
  const float* b_enc1 = (const float*)d_in[7];
  const float* W_enc2 = (const float*)d_in[8];
  const float* b_enc2 = (const float*)d_in[9];
  const float* W_r1g1 = (const float*)d_in[10];
  const float* b_r1g1 = (const float*)d_in[11];
  const float* W_r1g2 = (const float*)d_in[12];
  const float* b_r1g2 = (const float*)d_in[13];
  const float* W_r2g1 = (const float*)d_in[14];
  const float* b_r2g1 = (const float*)d_in[15];
  const float* W_r2g2 = (const float*)d_in[16];
  const float* b_r2g2 = (const float*)d_in[17];
  const float* W_l1 = (const float*)d_in[18];
  const float* b_l1 = (const float*)d_in[19];
  const float* W_l2 = (const float*)d_in[20];
  const float* b_l2 = (const float*)d_in[21];

  float* out = (float*)d_out;

  char* ws = (char*)d_ws;
  size_t off = 0;
  auto carve = [&](size_t bytes) {
    char* p = ws + off;
    off = (off + bytes + 255) & ~(size_t)255;
    return p;
  };
  // ACT: L1 out (MT2 x 512 f32) then L2 out (MT2 x 1024 f32). L3 output is
  // never materialized (fused atomic pool).
  float* ACT = (float*)carve((size_t)MT2 * 1024 * 4);
  unsigned short* Ah = (unsigned short*)carve((size_t)MT2 * 1024 * 2);
  unsigned short* Al = (unsigned short*)carve((size_t)MT2 * 1024 * 2);
  // weight splits (transposed [N][K] bf16 hi/lo)
  unsigned short* W1h_a = (unsigned short*)carve((size_t)512 * 128 * 2);
  unsigned short* W1l_a = (unsigned short*)carve((size_t)512 * 128 * 2);
  unsigned short* W1h_b = (unsigned short*)carve((size_t)512 * 128 * 2);
  unsigned short* W1l_b = (unsigned short*)carve((size_t)512 * 128 * 2);
  unsigned short* W2h_a = (unsigned short*)carve((size_t)1024 * 512 * 2);
  unsigned short* W2l_a = (unsigned short*)carve((size_t)1024 * 512 * 2);
  unsigned short* W2h_b = (unsigned short*)carve((size_t)1024 * 512 * 2);
  unsigned short* W2l_b = (unsigned short*)carve((size_t)1024 * 512 * 2);
  unsigned short* W3h_a = (unsigned short*)carve((size_t)2048 * 1024 * 2);
  unsigned short* W3l_a = (unsigned short*)carve((size_t)2048 * 1024 * 2);
  unsigned short* W3h_b = (unsigned short*)carve((size_t)2048 * 1024 * 2);
  unsigned short* W3l_b = (unsigned short*)carve((size_t)2048 * 1024 * 2);
  float* P2   = (float*)carve((size_t)2 * NG * 2048 * 4);   // pooled, both branches
  float* ZZ   = (float*)carve((size_t)NG * 1024 * 4);
  float* PART = (float*)carve((size_t)16 * NG * 1024 * 4);  // split-K partials
  float* dinv = (float*)carve((size_t)MT2 * 4);
  int* cnt     = (int*)carve((size_t)MT2 * 4);
  int* row_ptr = (int*)carve((size_t)(MT2 + 1) * 4);
  int* cursor  = (int*)carve((size_t)MT2 * 4);
  int* csr_src = (int*)carve((size_t)2 * NE * 4);
  (void)ws_size; (void)n_in; (void)in_sizes; (void)out_size;

  // weight transpose+split, both branches batched via grid.z
  k_wsplit2<<<dim3(512 / 32, 128 / 32, 2), 256, 0, stream>>>(
      W_enc1, W1h_a, W1l_a, W_enc2, W1h_b, W1l_b, 128, 512);
  k_wsplit2<<<dim3(1024 / 32, 512 / 32, 2), 256, 0, stream>>>(
      W_r1g1, W2h_a, W2l_a, W_r2g1, W2h_b, W2l_b, 512, 1024);
  k_wsplit2<<<dim3(2048 / 32, 1024 / 32, 2), 256, 0, stream>>>(
      W_r1g2, W3h_a, W3l_a, W_r2g2, W3h_b, W3l_b, 1024, 2048);

  // batched CSR build
  hipMemsetAsync(cnt, 0, (size_t)MT2 * 4, stream);
  k_count2<<<(2 * NE + 255) / 256, 256, 0, stream>>>(ei_s, ei_t, cnt);
  k_scan<<<1, 256, 0, stream>>>(cnt, row_ptr, cursor, dinv);
  k_scatter2<<<(2 * NE + 255) / 256, 256, 0, stream>>>(ei_s, ei_t, cursor, csr_src);

  // L1: agg (dual input) [F=128] -> GEMM M=MT2, N=512, K=128 (no relu)
  k_agg_x<4, true><<<NB2 * 4, 256, 0, stream>>>(
      x_s, x_t, Ah, Al, row_ptr, csr_src, dinv);
  k_mgemm<false, 4><<<4 * (MT2 / 128), 256, 0, stream>>>(
      Ah, Al, W1h_a, W1l_a, W1h_b, W1l_b, b_enc1, b_enc2, ACT, 512, 128);

  // L2: agg [F=512] -> relu GEMM M=MT2, N=1024, K=512
  k_agg_x<16, false><<<NB2 * 16, 256, 0, stream>>>(
      ACT, nullptr, Ah, Al, row_ptr, csr_src, dinv);
  k_mgemm<true, 8><<<8 * (MT2 / 128), 256, 0, stream>>>(
      Ah, Al, W2h_a, W2l_a, W2h_b, W2l_b, b_r1g1, b_r2g1, ACT, 1024, 512);

  // L3: agg [F=1024] -> merged 256^2 GEMM with fused atomicMax pool
  k_agg_x<32, false><<<NB2 * 32, 256, 0, stream>>>(
      ACT, nullptr, Ah, Al, row_ptr, csr_src, dinv);
  hipMemsetAsync(P2, 0, (size_t)2 * NG * 2048 * 4, stream);
  k_mgemm3<<<8 * (MT2 / 256), 512, 0, stream>>>(
      Ah, Al, W3h_a, W3l_a, W3h_b, W3l_b, b_r1g2, b_r2g2,
      xs_batch, xt_batch, P2, 2048, 1024);

  // MLP head, split-K fp32 (Z = P_s + P_t fused into A-load)
  k_gemm_sk<<<dim3(1024 / 64, 2, 16), 256, 0, stream>>>(
      P2, P2 + (size_t)NG * 2048, W_l1, PART, NG, 1024, 2048, 128);
  k_reduce<false><<<(NG * 1024 + 255) / 256, 256, 0, stream>>>(
      PART, b_l1, ZZ, nullptr, NG * 1024, 1024, 16);

  const int OUTN = 1317;
  k_gemm_sk<<<dim3((OUTN + 63) / 64, 2, 8), 256, 0, stream>>>(
      ZZ, nullptr, W_l2, PART, NG, OUTN, 1024, 128);
  k_reduce<true><<<(NG * OUTN + 255) / 256, 256, 0, stream>>>(
      PART, b_l2, out, out + (size_t)NG * OUTN, NG * OUTN, OUTN, 8);
}

// Round 14
// 793.470 us; speedup vs baseline: 1.0227x; 1.0227x over previous
//
#include <hip/hip_runtime.h>
#include <cstdint>
#include <cstddef>

// ---------------------------------------------------------------------------
// SSLModel: dual-branch GCN + global max pool + MLP head.
// Round 14: R13's reorder reverted (regressed: barriers lock waves either
// way; holding 24 ds_read dests across MFMA raised pressure). L3 goes back
// to the PROVEN 128^2 tile/schedule (R10/R12 k_mgemm loop, 64KB LDS,
// 2 blocks/CU) but KEEPS R12's fused bias+ReLU+atomicMax pool epilogue and
// single merged launch (k_mgemmP). L1/L2/agg/CSR/head = R12 exactly.
// ---------------------------------------------------------------------------

#define NN 10000      // nodes per graph-batch
#define NNP2 10240    // padded to 256 (40 tiles; 80x128)
#define MT2 20480     // 2*NNP2 merged rows
#define NB2 640       // MT2/32 node-blocks
#define NE 160000     // edges per branch
#define NG 128        // graphs per branch

typedef short bf16x8 __attribute__((ext_vector_type(8)));
typedef float f32x4 __attribute__((ext_vector_type(4)));

__device__ __forceinline__ unsigned short f2bf(float x) {
  unsigned u = __float_as_uint(x);
  u += 0x7FFFu + ((u >> 16) & 1u);   // RNE (finite inputs)
  return (unsigned short)(u >> 16);
}
__device__ __forceinline__ float bf2f(unsigned short h) {
  return __uint_as_float(((unsigned)h) << 16);
}
__device__ __forceinline__ void fma4(float4& d, float s, const float4& u) {
  d.x = fmaf(s, u.x, d.x);
  d.y = fmaf(s, u.y, d.y);
  d.z = fmaf(s, u.z, d.z);
  d.w = fmaf(s, u.w, d.w);
}

#define GLOAD_LDS16(gp, lp)                                                  \
  __builtin_amdgcn_global_load_lds(                                          \
      (const __attribute__((address_space(1))) void*)(gp),                   \
      (__attribute__((address_space(3))) void*)(lp), 16, 0, 0)

// ---------------- CSR build (both branches batched) ----------------

__global__ void k_count2(const int* __restrict__ eis, const int* __restrict__ eit,
                         int* __restrict__ cnt) {
  int i = blockIdx.x * blockDim.x + threadIdx.x;
  if (i >= 2 * NE) return;
  int d;
  if (i < NE) d = eis[NE + i];
  else        d = eit[NE + (i - NE)] + NNP2;
  atomicAdd(&cnt[d], 1);
}

// scan + dinv (single block, 256 thr, n = MT2)
__global__ void k_scan(const int* __restrict__ cnt, int* __restrict__ row_ptr,
                       int* __restrict__ cursor, float* __restrict__ dinv) {
  __shared__ int part[256];
  __shared__ int partex[257];
  int t = threadIdx.x;
  const int n = MT2;
  const int CH = n / 256;
  int base = t * CH;
  int s = 0;
  for (int i = 0; i < CH; ++i) s += cnt[base + i];
  part[t] = s;
  __syncthreads();
  if (t == 0) {
    int acc = 0;
    for (int i = 0; i < 256; ++i) { partex[i] = acc; acc += part[i]; }
    partex[256] = acc;
  }
  __syncthreads();
  int acc = partex[t];
  for (int i = 0; i < CH; ++i) {
    int idx = base + i;
    row_ptr[idx] = acc;
    cursor[idx]  = acc;
    dinv[idx] = rsqrtf((float)cnt[idx] + 1.0f);
    acc += cnt[idx];
  }
  if (t == 255) row_ptr[n] = partex[256];
}

// src-only CSR (weight recomputed in agg), grouped by dst_global
__global__ void k_scatter2(const int* __restrict__ eis, const int* __restrict__ eit,
                           int* __restrict__ cursor, int* __restrict__ csr_src) {
  int i = blockIdx.x * blockDim.x + threadIdx.x;
  if (i >= 2 * NE) return;
  int s, d;
  if (i < NE) { s = eis[i]; d = eis[NE + i]; }
  else { int j = i - NE; s = eit[j] + NNP2; d = eit[NE + j] + NNP2; }
  int pos = atomicAdd(&cursor[d], 1);
  csr_src[pos] = s;
}

// ---------------- XCD-pinned chunk-column aggregate + bf16 split -----------
template <int NCH, bool DUAL>
__global__ __launch_bounds__(256) void k_agg_x(
    const float* __restrict__ in0, const float* __restrict__ in1,
    unsigned short* __restrict__ Ah, unsigned short* __restrict__ Al,
    const int* __restrict__ row_ptr, const int* __restrict__ csr_src,
    const float* __restrict__ dinv) {
  constexpr int F4TOT = NCH * 8;
  const int bid = blockIdx.x;
  const int xcd = bid & 7;
  const int seq = bid >> 3;
  int chunk, nodeblk;
  if constexpr (NCH >= 8) {
    int phase = seq / NB2;
    nodeblk = seq - phase * NB2;
    chunk = phase * 8 + xcd;
  } else {  // NCH == 4: two XCDs share a chunk (even/odd node-blocks)
    chunk = xcd >> 1;
    nodeblk = (seq << 1) | (xcd & 1);
  }
  const int t = threadIdx.x;
  const int node = nodeblk * 32 + (t >> 3);
  const int f4 = chunk * 8 + (t & 7);

  size_t o = (size_t)node * F4TOT + f4;
  ushort4* oh = (ushort4*)Ah + o;
  ushort4* ol = (ushort4*)Al + o;
  int local = (node < NNP2) ? node : (node - NNP2);
  if (local >= NN) {   // pad row
    *oh = make_ushort4(0, 0, 0, 0);
    *ol = make_ushort4(0, 0, 0, 0);
    return;
  }
  const float4* i0 = (const float4*)in0;
  const float4* i1 = (const float4*)in1;
  auto rowp = [&](int g) -> const float4* {
    if (DUAL)
      return (g < NNP2) ? (i0 + (size_t)g * F4TOT)
                        : (i1 + (size_t)(g - NNP2) * F4TOT);
    return i0 + (size_t)g * F4TOT;
  };

  float di = dinv[node];
  float sw = di * di;
  float4 v = rowp(node)[f4];
  float4 acc;
  acc.x = sw * v.x; acc.y = sw * v.y; acc.z = sw * v.z; acc.w = sw * v.w;

  const int e0 = row_ptr[node], e1 = row_ptr[node + 1];
  int e = e0;
  for (; e + 4 <= e1; e += 4) {
    int s0 = csr_src[e], s1 = csr_src[e + 1];
    int s2 = csr_src[e + 2], s3 = csr_src[e + 3];
    float4 u0 = rowp(s0)[f4];
    float4 u1 = rowp(s1)[f4];
    float4 u2 = rowp(s2)[f4];
    float4 u3 = rowp(s3)[f4];
    float w0 = dinv[s0] * di, w1 = dinv[s1] * di;
    float w2 = dinv[s2] * di, w3 = dinv[s3] * di;
    fma4(acc, w0, u0);
    fma4(acc, w1, u1);
    fma4(acc, w2, u2);
    fma4(acc, w3, u3);
  }
  for (; e < e1; ++e) {
    int s = csr_src[e];
    float4 u = rowp(s)[f4];
    fma4(acc, dinv[s] * di, u);
  }

  ushort4 h, l;
  h.x = f2bf(acc.x); l.x = f2bf(acc.x - bf2f(h.x));
  h.y = f2bf(acc.y); l.y = f2bf(acc.y - bf2f(h.y));
  h.z = f2bf(acc.z); l.z = f2bf(acc.z - bf2f(h.z));
  h.w = f2bf(acc.w); l.w = f2bf(acc.w - bf2f(h.w));
  *oh = h;
  *ol = l;
}

// ---------------- weight transpose + split, 2 weight sets batched --------
__global__ __launch_bounds__(256) void k_wsplit2(
    const float* __restrict__ W0, unsigned short* __restrict__ H0,
    unsigned short* __restrict__ L0,
    const float* __restrict__ W1, unsigned short* __restrict__ H1,
    unsigned short* __restrict__ L1, int K, int N) {
  const float* W = blockIdx.z ? W1 : W0;
  unsigned short* Ht = blockIdx.z ? H1 : H0;
  unsigned short* Lt = blockIdx.z ? L1 : L0;
  __shared__ float tile[32][33];
  int nb = blockIdx.x * 32, kb = blockIdx.y * 32;
  int tx = threadIdx.x & 31, ty = threadIdx.x >> 5;
#pragma unroll
  for (int r = ty; r < 32; r += 8)
    tile[r][tx] = W[(size_t)(kb + r) * N + nb + tx];
  __syncthreads();
#pragma unroll
  for (int r = ty; r < 32; r += 8) {
    float x = tile[tx][r];  // = W[kb+tx][nb+r]
    unsigned short h = f2bf(x);
    unsigned short lo = f2bf(x - bf2f(h));
    size_t o = (size_t)(nb + r) * K + kb + tx;
    Ht[o] = h;
    Lt[o] = lo;
  }
}

// ---------------- split-bf16 MFMA GEMM 128x128 (R12 schedule) -------------
template <bool RELU, int GX>
__global__ __launch_bounds__(256) void k_mgemm(
    const unsigned short* __restrict__ Ah, const unsigned short* __restrict__ Al,
    const unsigned short* __restrict__ Bh_a, const unsigned short* __restrict__ Bl_a,
    const unsigned short* __restrict__ Bh_b, const unsigned short* __restrict__ Bl_b,
    const float* __restrict__ bias_a, const float* __restrict__ bias_b,
    float* __restrict__ C, int N, int K) {
  __shared__ char smem[65536];  // 2 x [Ah|Al|Bh|Bl] x 8KiB
  const int t = threadIdx.x;
  const int w = t >> 6, l = t & 63;

  const int bid = blockIdx.x;
  const int bn_ = bid & (GX - 1), bm_ = bid / GX;
  const int bm = bm_ * 128, bn = bn_ * 128;
  const bool sec = bm >= NNP2;
  const unsigned short* Bh = sec ? Bh_b : Bh_a;
  const unsigned short* Bl = sec ? Bl_b : Bl_a;
  const float* bias = sec ? bias_b : bias_a;

  const int wr = w >> 1, wc = w & 1;

  f32x4 acc[4][4] = {};

  // staging: wave w owns matrix w entirely (8 x 1KiB chunks)
  const unsigned short* g0 = (w == 0) ? Ah : (w == 1) ? Al : (w == 2) ? Bh : Bl;
  const int rb = (w < 2) ? bm : bn;
  const unsigned short* gbase = g0 + (size_t)(rb + (l & 15)) * K + ((l >> 4) * 8);
  const int sdoff = w * 8192 + l * 16;
  const int saoff = wr * 4096 + l * 16;          // A-hi frags; A-lo at +8192
  const int sboff = 16384 + wc * 4096 + l * 16;  // B-hi frags; B-lo at +8192

  const int nt = K >> 5;

#define STAGE(kt, b)                                                         \
  {                                                                          \
    const unsigned short* gk = gbase + ((kt) << 5);                          \
    char* sd = smem + (b)*32768 + sdoff;                                     \
    _Pragma("unroll") for (int s = 0; s < 8; ++s)                            \
        GLOAD_LDS16(gk + (size_t)s * 16 * K, sd + s * 1024);                 \
  }

  STAGE(0, 0)

  for (int kt = 0; kt < nt; ++kt) {
    const int cur = kt & 1;
    if (kt + 1 < nt) {
      STAGE(kt + 1, cur ^ 1)
      asm volatile("s_waitcnt vmcnt(8)" ::: "memory");  // tile kt landed
    } else {
      asm volatile("s_waitcnt vmcnt(0)" ::: "memory");
    }
    __builtin_amdgcn_sched_barrier(0);
    __builtin_amdgcn_s_barrier();  // collective: buf[cur] fully staged

    const char* sA = smem + cur * 32768 + saoff;
    const char* sB = smem + cur * 32768 + sboff;
    bf16x8 a[4][2], b[4][2];
#pragma unroll
    for (int i = 0; i < 4; ++i) {
      a[i][0] = *(const bf16x8*)(sA + i * 1024);
      a[i][1] = *(const bf16x8*)(sA + 8192 + i * 1024);
    }
#pragma unroll
    for (int j = 0; j < 4; ++j) {
      b[j][0] = *(const bf16x8*)(sB + j * 1024);
      b[j][1] = *(const bf16x8*)(sB + 8192 + j * 1024);
    }
    asm volatile("s_waitcnt lgkmcnt(0)" ::: "memory");  // frag reads done
    __builtin_amdgcn_sched_barrier(0);
    __builtin_amdgcn_s_barrier();  // all reads done; next STAGE may overwrite

    __builtin_amdgcn_s_setprio(1);
#pragma unroll
    for (int i = 0; i < 4; ++i)
#pragma unroll
      for (int j = 0; j < 4; ++j) {
        acc[i][j] = __builtin_amdgcn_mfma_f32_16x16x32_bf16(a[i][0], b[j][0], acc[i][j], 0, 0, 0);
        acc[i][j] = __builtin_amdgcn_mfma_f32_16x16x32_bf16(a[i][0], b[j][1], acc[i][j], 0, 0, 0);
        acc[i][j] = __builtin_amdgcn_mfma_f32_16x16x32_bf16(a[i][1], b[j][0], acc[i][j], 0, 0, 0);
      }
    __builtin_amdgcn_s_setprio(0);
  }
#undef STAGE

  // epilogue: C/D layout: col = lane&15, row = (lane>>4)*4 + reg
  const int r0 = bm + wr * 64 + ((l >> 4) << 2);
  const int c0 = bn + wc * 64 + (l & 15);
#pragma unroll
  for (int j = 0; j < 4; ++j) {
    const int col = c0 + j * 16;
    const float bv = bias[col];
#pragma unroll
    for (int i = 0; i < 4; ++i) {
      const int row = r0 + i * 16;
#pragma unroll
      for (int r = 0; r < 4; ++r) {
        float v = acc[i][j][r] + bv;
        if (RELU) v = fmaxf(v, 0.f);
        C[(size_t)(row + r) * N + col] = v;
      }
    }
  }
}

// ---------------- L3: 128x128 mgemm + fused bias/ReLU/atomicMax pool ------
// Identical loop/schedule to k_mgemm (the proven R12 form); epilogue does
// bias+ReLU then atomicMax into P2 (int-reinterpret max, valid for >=0
// floats; P2 pre-zeroed). Output matrix never materialized.
__global__ __launch_bounds__(256) void k_mgemmP(
    const unsigned short* __restrict__ Ah, const unsigned short* __restrict__ Al,
    const unsigned short* __restrict__ Bh_a, const unsigned short* __restrict__ Bl_a,
    const unsigned short* __restrict__ Bh_b, const unsigned short* __restrict__ Bl_b,
    const float* __restrict__ bias_a, const float* __restrict__ bias_b,
    const int* __restrict__ bs, const int* __restrict__ bt,
    float* __restrict__ P2, int N, int K) {
  __shared__ char smem[65536];
  const int t = threadIdx.x;
  const int w = t >> 6, l = t & 63;

  const int bid = blockIdx.x;
  const int bn_ = bid & 15, bm_ = bid >> 4;   // GX = 16 (N = 2048)
  const int bm = bm_ * 128, bn = bn_ * 128;
  const bool sec = bm >= NNP2;                // 10240 % 128 == 0: no straddle
  const unsigned short* Bh = sec ? Bh_b : Bh_a;
  const unsigned short* Bl = sec ? Bl_b : Bl_a;
  const float* bias = sec ? bias_b : bias_a;
  const int* batch = sec ? bt : bs;
  float* P2g = P2 + (sec ? (size_t)NG * 2048 : 0);
  const int lbase = bm - (sec ? NNP2 : 0);    // branch-local row base

  const int wr = w >> 1, wc = w & 1;

  f32x4 acc[4][4] = {};

  const unsigned short* g0 = (w == 0) ? Ah : (w == 1) ? Al : (w == 2) ? Bh : Bl;
  const int rb = (w < 2) ? bm : bn;
  const unsigned short* gbase = g0 + (size_t)(rb + (l & 15)) * K + ((l >> 4) * 8);
  const int sdoff = w * 8192 + l * 16;
  const int saoff = wr * 4096 + l * 16;
  const int sboff = 16384 + wc * 4096 + l * 16;

  const int nt = K >> 5;

#define STAGEP(kt, b)                                                        \
  {                                                                          \
    const unsigned short* gk = gbase + ((kt) << 5);                          \
    char* sd = smem + (b)*32768 + sdoff;                                     \
    _Pragma("unroll") for (int s = 0; s < 8; ++s)                            \
        GLOAD_LDS16(gk + (size_t)s * 16 * K, sd + s * 1024);                 \
  }

  STAGEP(0, 0)

  for (int kt = 0; kt < nt; ++kt) {
    const int cur = kt & 1;
    if (kt + 1 < nt) {
      STAGEP(kt + 1, cur ^ 1)
      asm volatile("s_waitcnt vmcnt(8)" ::: "memory");
    } else {
      asm volatile("s_waitcnt vmcnt(0)" ::: "memory");
    }
    __builtin_amdgcn_sched_barrier(0);
    __builtin_amdgcn_s_barrier();

    const char* sA = smem + cur * 32768 + saoff;
    const char* sB = smem + cur * 32768 + sboff;
    bf16x8 a[4][2], b[4][2];
#pragma unroll
    for (int i = 0; i < 4; ++i) {
      a[i][0] = *(const bf16x8*)(sA + i * 1024);
      a[i][1] = *(const bf16x8*)(sA + 8192 + i * 1024);
    }
#pragma unroll
    for (int j = 0; j < 4; ++j) {
      b[j][0] = *(const bf16x8*)(sB + j * 1024);
      b[j][1] = *(const bf16x8*)(sB + 8192 + j * 1024);
    }
    asm volatile("s_waitcnt lgkmcnt(0)" ::: "memory");
    __builtin_amdgcn_sched_barrier(0);
    __builtin_amdgcn_s_barrier();

    __builtin_amdgcn_s_setprio(1);
#pragma unroll
    for (int i = 0; i < 4; ++i)
#pragma unroll
      for (int j = 0; j < 4; ++j) {
        acc[i][j] = __builtin_amdgcn_mfma_f32_16x16x32_bf16(a[i][0], b[j][0], acc[i][j], 0, 0, 0);
        acc[i][j] = __builtin_amdgcn_mfma_f32_16x16x32_bf16(a[i][0], b[j][1], acc[i][j], 0, 0, 0);
        acc[i][j] = __builtin_amdgcn_mfma_f32_16x16x32_bf16(a[i][1], b[j][0], acc[i][j], 0, 0, 0);
      }
    __builtin_amdgcn_s_setprio(0);
  }
#undef STAGEP

  // epilogue: bias + ReLU + segmented atomicMax pool (no C store)
  const int r0l = lbase + wr * 64 + ((l >> 4) << 2);
  const int c0 = bn + wc * 64 + (l & 15);
#pragma unroll
  for (int j = 0; j < 4; ++j) {
    const int col = c0 + j * 16;
    const float bv = bias[col];
    float* Pcol = P2g + col;
#pragma unroll
    for (int i = 0; i < 4; ++i) {
      const int rl = r0l + i * 16;
      if (rl >= NN) continue;
      float v0 = fmaxf(acc[i][j][0] + bv, 0.f);
      float v1 = fmaxf(acc[i][j][1] + bv, 0.f);
      float v2 = fmaxf(acc[i][j][2] + bv, 0.f);
      float v3 = fmaxf(acc[i][j][3] + bv, 0.f);
      if (rl + 3 < NN) {
        int g0i = batch[rl], g3i = batch[rl + 3];
        if (g0i == g3i) {
          float m = fmaxf(fmaxf(v0, v1), fmaxf(v2, v3));
          atomicMax((int*)(Pcol + (size_t)g0i * 2048), __float_as_int(m));
        } else {
          int g1i = batch[rl + 1], g2i = batch[rl + 2];
          atomicMax((int*)(Pcol + (size_t)g0i * 2048), __float_as_int(v0));
          atomicMax((int*)(Pcol + (size_t)g1i * 2048), __float_as_int(v1));
          atomicMax((int*)(Pcol + (size_t)g2i * 2048), __float_as_int(v2));
          atomicMax((int*)(Pcol + (size_t)g3i * 2048), __float_as_int(v3));
        }
      } else {
        float vv[4] = {v0, v1, v2, v3};
        for (int r = 0; r < 4; ++r) {
          if (rl + r < NN) {
            int g = batch[rl + r];
            atomicMax((int*)(Pcol + (size_t)g * 2048), __float_as_int(vv[r]));
          }
        }
      }
    }
  }
}

// ---------------- split-K fp32 GEMM for the tiny head (M=128) -------------
__global__ __launch_bounds__(256) void k_gemm_sk(
    const float* __restrict__ A, const float* __restrict__ A2,
    const float* __restrict__ B,
    float* __restrict__ PART, int M, int N, int K, int KS) {
  __shared__ float As[32][64];
  __shared__ float Bs[32][64];

  int t = threadIdx.x;
  int tx = t & 15, ty = t >> 4;
  int bm = blockIdx.y * 64, bn = blockIdx.x * 64;
  int kbeg = blockIdx.z * KS, kend = kbeg + KS;

  float acc[4][4] = {};

  int arow0 = t >> 3;
  int ak4 = (t & 7) * 4;
  int brow0 = t >> 4;
  int bn4 = (t & 15) * 4;
  const bool n4al = (N & 3) == 0;

  for (int k0 = kbeg; k0 < kend; k0 += 32) {
#pragma unroll
    for (int c = 0; c < 2; ++c) {
      int row = arow0 + c * 32;
      int gr = bm + row;
      float4 v = make_float4(0.f, 0.f, 0.f, 0.f);
      if (gr < M) {
        v = *(const float4*)&A[(size_t)gr * K + k0 + ak4];
        if (A2) {
          float4 v2 = *(const float4*)&A2[(size_t)gr * K + k0 + ak4];
          v.x += v2.x; v.y += v2.y; v.z += v2.z; v.w += v2.w;
        }
      }
      As[ak4 + 0][row] = v.x;
      As[ak4 + 1][row] = v.y;
      As[ak4 + 2][row] = v.z;
      As[ak4 + 3][row] = v.w;
    }
#pragma unroll
    for (int c = 0; c < 2; ++c) {
      int row = brow0 + c * 16;
      int gc = bn + bn4;
      const float* bp = &B[(size_t)(k0 + row) * N + gc];
      float4 v;
      if (n4al && gc + 3 < N) {
        v = *(const float4*)bp;
      } else {
        v = make_float4(0.f, 0.f, 0.f, 0.f);
        if (gc < N) v.x = bp[0];
        if (gc + 1 < N) v.y = bp[1];
        if (gc + 2 < N) v.z = bp[2];
        if (gc + 3 < N) v.w = bp[3];
      }
      *(float4*)&Bs[row][bn4] = v;
    }
    __syncthreads();

#pragma unroll
    for (int kk = 0; kk < 32; ++kk) {
      float4 a = *(const float4*)&As[kk][ty * 4];
      float4 b = *(const float4*)&Bs[kk][tx * 4];
      float av[4] = {a.x, a.y, a.z, a.w};
      float bv[4] = {b.x, b.y, b.z, b.w};
#pragma unroll
      for (int i = 0; i < 4; ++i)
#pragma unroll
        for (int j = 0; j < 4; ++j)
          acc[i][j] = fmaf(av[i], bv[j], acc[i][j]);
    }
    __syncthreads();
  }

  float* P = PART + (size_t)blockIdx.z * M * N;
  int r0 = bm + ty * 4, c0 = bn + tx * 4;
#pragma unroll
  for (int i = 0; i < 4; ++i) {
    int r = r0 + i;
    if (r < M) {
#pragma unroll
      for (int j = 0; j < 4; ++j) {
        int c = c0 + j;
        if (c < N) P[(size_t)r * N + c] = acc[i][j];
      }
    }
  }
}

// reduce SK partials + bias (+relu or logits+sigmoid)
template <bool SIG>
__global__ void k_reduce(const float* __restrict__ PART,
                         const float* __restrict__ bias,
                         float* __restrict__ C, float* __restrict__ C2,
                         int MN, int N, int SK) {
  int i = blockIdx.x * blockDim.x + threadIdx.x;
  if (i >= MN) return;
  float s = 0.f;
  for (int z = 0; z < SK; ++z) s += PART[(size_t)z * MN + i];
  s += bias[i % N];
  if (SIG) {
    C[i] = s;
    C2[i] = 1.0f / (1.0f + __expf(-s));
  } else {
    C[i] = fmaxf(s, 0.f);
  }
}

// ---------------- entry ----------------

extern "C" void kernel_launch(void* const* d_in, const int* in_sizes, int n_in,
                              void* d_out, int out_size, void* d_ws, size_t ws_size,
                              hipStream_t stream) {
  const float* x_s = (const float*)d_in[0];
  const float* x_t = (const float*)d_in[1];
  const int* ei_s = (const int*)d_in[2];
  const int* ei_t = (const int*)d_in[3];
  const int* xs_batch = (const int*)d_in[4];
  const int* xt_batch = (const int*)d_in[5];
  const float* W_enc1 = (const float*)d_in[6];
  const float* b_enc1 = (const float*)d_in[7];
  const float* W_enc2 = (const float*)d_in[8];
  const float* b_enc2 = (const float*)d_in[9];
  const float* W_r1g1 = (const float*)d_in[10];
  const float* b_r1g1 = (const float*)d_in[11];
  const float* W_r1g2 = (const float*)d_in[12];
  const float* b_r1g2 = (const float*)d_in[13];
  const float* W_r2g1 = (const float*)d_in[14];
  const float* b_r2g1 = (const float*)d_in[15];
  const float* W_r2g2 = (const float*)d_in[16];
  const float* b_r2g2 = (const float*)d_in[17];
  const float* W_l1 = (const float*)d_in[18];
  const float* b_l1 = (const float*)d_in[19];
  const float* W_l2 = (const float*)d_in[20];
  const float* b_l2 = (const float*)d_in[21];

  float* out = (float*)d_out;

  char* ws = (char*)d_ws;
  size_t off = 0;
  auto carve = [&](size_t bytes) {
    char* p = ws + off;
    off = (off + bytes + 255) & ~(size_t)255;
    return p;
  };
  // ACT: L1 out (MT2 x 512 f32) then L2 out (MT2 x 1024 f32). L3 output is
  // never materialized (fused atomic pool).
  float* ACT = (float*)carve((size_t)MT2 * 1024 * 4);
  unsigned short* Ah = (unsigned short*)carve((size_t)MT2 * 1024 * 2);
  unsigned short* Al = (unsigned short*)carve((size_t)MT2 * 1024 * 2);
  // weight splits (transposed [N][K] bf16 hi/lo)
  unsigned short* W1h_a = (unsigned short*)carve((size_t)512 * 128 * 2);
  unsigned short* W1l_a = (unsigned short*)carve((size_t)512 * 128 * 2);
  unsigned short* W1h_b = (unsigned short*)carve((size_t)512 * 128 * 2);
  unsigned short* W1l_b = (unsigned short*)carve((size_t)512 * 128 * 2);
  unsigned short* W2h_a = (unsigned short*)carve((size_t)1024 * 512 * 2);
  unsigned short* W2l_a = (unsigned short*)carve((size_t)1024 * 512 * 2);
  unsigned short* W2h_b = (unsigned short*)carve((size_t)1024 * 512 * 2);
  unsigned short* W2l_b = (unsigned short*)carve((size_t)1024 * 512 * 2);
  unsigned short* W3h_a = (unsigned short*)carve((size_t)2048 * 1024 * 2);
  unsigned short* W3l_a = (unsigned short*)carve((size_t)2048 * 1024 * 2);
  unsigned short* W3h_b = (unsigned short*)carve((size_t)2048 * 1024 * 2);
  unsigned short* W3l_b = (unsigned short*)carve((size_t)2048 * 1024 * 2);
  float* P2   = (float*)carve((size_t)2 * NG * 2048 * 4);   // pooled, both branches
  float* ZZ   = (float*)carve((size_t)NG * 1024 * 4);
  float* PART = (float*)carve((size_t)16 * NG * 1024 * 4);  // split-K partials
  float* dinv = (float*)carve((size_t)MT2 * 4);
  int* cnt     = (int*)carve((size_t)MT2 * 4);
  int* row_ptr = (int*)carve((size_t)(MT2 + 1) * 4);
  int* cursor  = (int*)carve((size_t)MT2 * 4);
  int* csr_src = (int*)carve((size_t)2 * NE * 4);
  (void)ws_size; (void)n_in; (void)in_sizes; (void)out_size;

  // weight transpose+split, both branches batched via grid.z
  k_wsplit2<<<dim3(512 / 32, 128 / 32, 2), 256, 0, stream>>>(
      W_enc1, W1h_a, W1l_a, W_enc2, W1h_b, W1l_b, 128, 512);
  k_wsplit2<<<dim3(1024 / 32, 512 / 32, 2), 256, 0, stream>>>(
      W_r1g1, W2h_a, W2l_a, W_r2g1, W2h_b, W2l_b, 512, 1024);
  k_wsplit2<<<dim3(2048 / 32, 1024 / 32, 2), 256, 0, stream>>>(
      W_r1g2, W3h_a, W3l_a, W_r2g2, W3h_b, W3l_b, 1024, 2048);

  // batched CSR build
  hipMemsetAsync(cnt, 0, (size_t)MT2 * 4, stream);
  k_count2<<<(2 * NE + 255) / 256, 256, 0, stream>>>(ei_s, ei_t, cnt);
  k_scan<<<1, 256, 0, stream>>>(cnt, row_ptr, cursor, dinv);
  k_scatter2<<<(2 * NE + 255) / 256, 256, 0, stream>>>(ei_s, ei_t, cursor, csr_src);

  // L1: agg (dual input) [F=128] -> GEMM M=MT2, N=512, K=128 (no relu)
  k_agg_x<4, true><<<NB2 * 4, 256, 0, stream>>>(
      x_s, x_t, Ah, Al, row_ptr, csr_src, dinv);
  k_mgemm<false, 4><<<4 * (MT2 / 128), 256, 0, stream>>>(
      Ah, Al, W1h_a, W1l_a, W1h_b, W1l_b, b_enc1, b_enc2, ACT, 512, 128);

  // L2: agg [F=512] -> relu GEMM M=MT2, N=1024, K=512
  k_agg_x<16, false><<<NB2 * 16, 256, 0, stream>>>(
      ACT, nullptr, Ah, Al, row_ptr, csr_src, dinv);
  k_mgemm<true, 8><<<8 * (MT2 / 128), 256, 0, stream>>>(
      Ah, Al, W2h_a, W2l_a, W2h_b, W2l_b, b_r1g1, b_r2g1, ACT, 1024, 512);

  // L3: agg [F=1024] -> merged 128^2 GEMM with fused atomicMax pool
  k_agg_x<32, false><<<NB2 * 32, 256, 0, stream>>>(
      ACT, nullptr, Ah, Al, row_ptr, csr_src, dinv);
  hipMemsetAsync(P2, 0, (size_t)2 * NG * 2048 * 4, stream);
  k_mgemmP<<<16 * (MT2 / 128), 256, 0, stream>>>(
      Ah, Al, W3h_a, W3l_a, W3h_b, W3l_b, b_r1g2, b_r2g2,
      xs_batch, xt_batch, P2, 2048, 1024);

  // MLP head, split-K fp32 (Z = P_s + P_t fused into A-load)
  k_gemm_sk<<<dim3(1024 / 64, 2, 16), 256, 0, stream>>>(
      P2, P2 + (size_t)NG * 2048, W_l1, PART, NG, 1024, 2048, 128);
  k_reduce<false><<<(NG * 1024 + 255) / 256, 256, 0, stream>>>(
      PART, b_l1, ZZ, nullptr, NG * 1024, 1024, 16);

  const int OUTN = 1317;
  k_gemm_sk<<<dim3((OUTN + 63) / 64, 2, 8), 256, 0, stream>>>(
      ZZ, nullptr, W_l2, PART, NG, OUTN, 1024, 128);
  k_reduce<true><<<(NG * OUTN + 255) / 256, 256, 0, stream>>>(
      PART, b_l2, out, out + (size_t)NG * OUTN, NG * OUTN, OUTN, 8);
}

// Round 15
// 780.835 us; speedup vs baseline: 1.0392x; 1.0162x over previous
//
#include <hip/hip_runtime.h>
#include <cstdint>
#include <cstddef>

// ---------------------------------------------------------------------------
// SSLModel: dual-branch GCN + global max pool + MLP head.
// Round 15: revert to R12 (best, 770us). ONE change: k_mgemm3 goes single-
// buffer (64KB, 2 blocks/CU) with the stage-under-MFMA pipeline:
//   vmcnt(0)+bar -> ds_read 24 frags -> lgkm(0)+bar (buffer free) ->
//   STAGE(kt+1) (async, flies under MFMAs) -> 96 MFMA.
// Loads get ~930cy of MFMA to land (~600cy latency) -> top-of-loop vmcnt(0)
// nearly free. Unlike R13 (dbuf: stage already issued before reads), here the
// stage ISSUE point moves under the MFMA cluster.
// ---------------------------------------------------------------------------

#define NN 10000      // nodes per graph-batch
#define NNP2 10240    // padded to 256 (40 tiles)
#define MT2 20480     // 2*NNP2 merged rows
#define NB2 640       // MT2/32 node-blocks
#define NE 160000     // edges per branch
#define NG 128        // graphs per branch

typedef short bf16x8 __attribute__((ext_vector_type(8)));
typedef float f32x4 __attribute__((ext_vector_type(4)));

__device__ __forceinline__ unsigned short f2bf(float x) {
  unsigned u = __float_as_uint(x);
  u += 0x7FFFu + ((u >> 16) & 1u);   // RNE (finite inputs)
  return (unsigned short)(u >> 16);
}
__device__ __forceinline__ float bf2f(unsigned short h) {
  return __uint_as_float(((unsigned)h) << 16);
}
__device__ __forceinline__ void fma4(float4& d, float s, const float4& u) {
  d.x = fmaf(s, u.x, d.x);
  d.y = fmaf(s, u.y, d.y);
  d.z = fmaf(s, u.z, d.z);
  d.w = fmaf(s, u.w, d.w);
}

#define GLOAD_LDS16(gp, lp)                                                  \
  __builtin_amdgcn_global_load_lds(                                          \
      (const __attribute__((address_space(1))) void*)(gp),                   \
      (__attribute__((address_space(3))) void*)(lp), 16, 0, 0)

// ---------------- CSR build (both branches batched) ----------------

__global__ void k_count2(const int* __restrict__ eis, const int* __restrict__ eit,
                         int* __restrict__ cnt) {
  int i = blockIdx.x * blockDim.x + threadIdx.x;
  if (i >= 2 * NE) return;
  int d;
  if (i < NE) d = eis[NE + i];
  else        d = eit[NE + (i - NE)] + NNP2;
  atomicAdd(&cnt[d], 1);
}

// scan + dinv (single block, 256 thr, n = MT2)
__global__ void k_scan(const int* __restrict__ cnt, int* __restrict__ row_ptr,
                       int* __restrict__ cursor, float* __restrict__ dinv) {
  __shared__ int part[256];
  __shared__ int partex[257];
  int t = threadIdx.x;
  const int n = MT2;
  const int CH = n / 256;
  int base = t * CH;
  int s = 0;
  for (int i = 0; i < CH; ++i) s += cnt[base + i];
  part[t] = s;
  __syncthreads();
  if (t == 0) {
    int acc = 0;
    for (int i = 0; i < 256; ++i) { partex[i] = acc; acc += part[i]; }
    partex[256] = acc;
  }
  __syncthreads();
  int acc = partex[t];
  for (int i = 0; i < CH; ++i) {
    int idx = base + i;
    row_ptr[idx] = acc;
    cursor[idx]  = acc;
    dinv[idx] = rsqrtf((float)cnt[idx] + 1.0f);
    acc += cnt[idx];
  }
  if (t == 255) row_ptr[n] = partex[256];
}

// src-only CSR (weight recomputed in agg), grouped by dst_global
__global__ void k_scatter2(const int* __restrict__ eis, const int* __restrict__ eit,
                           int* __restrict__ cursor, int* __restrict__ csr_src) {
  int i = blockIdx.x * blockDim.x + threadIdx.x;
  if (i >= 2 * NE) return;
  int s, d;
  if (i < NE) { s = eis[i]; d = eis[NE + i]; }
  else { int j = i - NE; s = eit[j] + NNP2; d = eit[NE + j] + NNP2; }
  int pos = atomicAdd(&cursor[d], 1);
  csr_src[pos] = s;
}

// ---------------- XCD-pinned chunk-column aggregate + bf16 split -----------
template <int NCH, bool DUAL>
__global__ __launch_bounds__(256) void k_agg_x(
    const float* __restrict__ in0, const float* __restrict__ in1,
    unsigned short* __restrict__ Ah, unsigned short* __restrict__ Al,
    const int* __restrict__ row_ptr, const int* __restrict__ csr_src,
    const float* __restrict__ dinv) {
  constexpr int F4TOT = NCH * 8;
  const int bid = blockIdx.x;
  const int xcd = bid & 7;
  const int seq = bid >> 3;
  int chunk, nodeblk;
  if constexpr (NCH >= 8) {
    int phase = seq / NB2;
    nodeblk = seq - phase * NB2;
    chunk = phase * 8 + xcd;
  } else {  // NCH == 4: two XCDs share a chunk (even/odd node-blocks)
    chunk = xcd >> 1;
    nodeblk = (seq << 1) | (xcd & 1);
  }
  const int t = threadIdx.x;
  const int node = nodeblk * 32 + (t >> 3);
  const int f4 = chunk * 8 + (t & 7);

  size_t o = (size_t)node * F4TOT + f4;
  ushort4* oh = (ushort4*)Ah + o;
  ushort4* ol = (ushort4*)Al + o;
  int local = (node < NNP2) ? node : (node - NNP2);
  if (local >= NN) {   // pad row
    *oh = make_ushort4(0, 0, 0, 0);
    *ol = make_ushort4(0, 0, 0, 0);
    return;
  }
  const float4* i0 = (const float4*)in0;
  const float4* i1 = (const float4*)in1;
  auto rowp = [&](int g) -> const float4* {
    if (DUAL)
      return (g < NNP2) ? (i0 + (size_t)g * F4TOT)
                        : (i1 + (size_t)(g - NNP2) * F4TOT);
    return i0 + (size_t)g * F4TOT;
  };

  float di = dinv[node];
  float sw = di * di;
  float4 v = rowp(node)[f4];
  float4 acc;
  acc.x = sw * v.x; acc.y = sw * v.y; acc.z = sw * v.z; acc.w = sw * v.w;

  const int e0 = row_ptr[node], e1 = row_ptr[node + 1];
  int e = e0;
  for (; e + 4 <= e1; e += 4) {
    int s0 = csr_src[e], s1 = csr_src[e + 1];
    int s2 = csr_src[e + 2], s3 = csr_src[e + 3];
    float4 u0 = rowp(s0)[f4];
    float4 u1 = rowp(s1)[f4];
    float4 u2 = rowp(s2)[f4];
    float4 u3 = rowp(s3)[f4];
    float w0 = dinv[s0] * di, w1 = dinv[s1] * di;
    float w2 = dinv[s2] * di, w3 = dinv[s3] * di;
    fma4(acc, w0, u0);
    fma4(acc, w1, u1);
    fma4(acc, w2, u2);
    fma4(acc, w3, u3);
  }
  for (; e < e1; ++e) {
    int s = csr_src[e];
    float4 u = rowp(s)[f4];
    fma4(acc, dinv[s] * di, u);
  }

  ushort4 h, l;
  h.x = f2bf(acc.x); l.x = f2bf(acc.x - bf2f(h.x));
  h.y = f2bf(acc.y); l.y = f2bf(acc.y - bf2f(h.y));
  h.z = f2bf(acc.z); l.z = f2bf(acc.z - bf2f(h.z));
  h.w = f2bf(acc.w); l.w = f2bf(acc.w - bf2f(h.w));
  *oh = h;
  *ol = l;
}

// ---------------- weight transpose + split, 2 weight sets batched --------
__global__ __launch_bounds__(256) void k_wsplit2(
    const float* __restrict__ W0, unsigned short* __restrict__ H0,
    unsigned short* __restrict__ L0,
    const float* __restrict__ W1, unsigned short* __restrict__ H1,
    unsigned short* __restrict__ L1, int K, int N) {
  const float* W = blockIdx.z ? W1 : W0;
  unsigned short* Ht = blockIdx.z ? H1 : H0;
  unsigned short* Lt = blockIdx.z ? L1 : L0;
  __shared__ float tile[32][33];
  int nb = blockIdx.x * 32, kb = blockIdx.y * 32;
  int tx = threadIdx.x & 31, ty = threadIdx.x >> 5;
#pragma unroll
  for (int r = ty; r < 32; r += 8)
    tile[r][tx] = W[(size_t)(kb + r) * N + nb + tx];
  __syncthreads();
#pragma unroll
  for (int r = ty; r < 32; r += 8) {
    float x = tile[tx][r];  // = W[kb+tx][nb+r]
    unsigned short h = f2bf(x);
    unsigned short lo = f2bf(x - bf2f(h));
    size_t o = (size_t)(nb + r) * K + kb + tx;
    Ht[o] = h;
    Lt[o] = lo;
  }
}

// ---------------- split-bf16 MFMA GEMM 128x128 (R12 schedule) -------------
template <bool RELU, int GX>
__global__ __launch_bounds__(256) void k_mgemm(
    const unsigned short* __restrict__ Ah, const unsigned short* __restrict__ Al,
    const unsigned short* __restrict__ Bh_a, const unsigned short* __restrict__ Bl_a,
    const unsigned short* __restrict__ Bh_b, const unsigned short* __restrict__ Bl_b,
    const float* __restrict__ bias_a, const float* __restrict__ bias_b,
    float* __restrict__ C, int N, int K) {
  __shared__ char smem[65536];  // 2 x [Ah|Al|Bh|Bl] x 8KiB
  const int t = threadIdx.x;
  const int w = t >> 6, l = t & 63;

  const int bid = blockIdx.x;
  const int bn_ = bid & (GX - 1), bm_ = bid / GX;
  const int bm = bm_ * 128, bn = bn_ * 128;
  const bool sec = bm >= NNP2;
  const unsigned short* Bh = sec ? Bh_b : Bh_a;
  const unsigned short* Bl = sec ? Bl_b : Bl_a;
  const float* bias = sec ? bias_b : bias_a;

  const int wr = w >> 1, wc = w & 1;

  f32x4 acc[4][4] = {};

  // staging: wave w owns matrix w entirely (8 x 1KiB chunks)
  const unsigned short* g0 = (w == 0) ? Ah : (w == 1) ? Al : (w == 2) ? Bh : Bl;
  const int rb = (w < 2) ? bm : bn;
  const unsigned short* gbase = g0 + (size_t)(rb + (l & 15)) * K + ((l >> 4) * 8);
  const int sdoff = w * 8192 + l * 16;
  const int saoff = wr * 4096 + l * 16;          // A-hi frags; A-lo at +8192
  const int sboff = 16384 + wc * 4096 + l * 16;  // B-hi frags; B-lo at +8192

  const int nt = K >> 5;

#define STAGE(kt, b)                                                         \
  {                                                                          \
    const unsigned short* gk = gbase + ((kt) << 5);                          \
    char* sd = smem + (b)*32768 + sdoff;                                     \
    _Pragma("unroll") for (int s = 0; s < 8; ++s)                            \
        GLOAD_LDS16(gk + (size_t)s * 16 * K, sd + s * 1024);                 \
  }

  STAGE(0, 0)

  for (int kt = 0; kt < nt; ++kt) {
    const int cur = kt & 1;
    if (kt + 1 < nt) {
      STAGE(kt + 1, cur ^ 1)
      asm volatile("s_waitcnt vmcnt(8)" ::: "memory");  // tile kt landed
    } else {
      asm volatile("s_waitcnt vmcnt(0)" ::: "memory");
    }
    __builtin_amdgcn_sched_barrier(0);
    __builtin_amdgcn_s_barrier();  // collective: buf[cur] fully staged

    const char* sA = smem + cur * 32768 + saoff;
    const char* sB = smem + cur * 32768 + sboff;
    bf16x8 a[4][2], b[4][2];
#pragma unroll
    for (int i = 0; i < 4; ++i) {
      a[i][0] = *(const bf16x8*)(sA + i * 1024);
      a[i][1] = *(const bf16x8*)(sA + 8192 + i * 1024);
    }
#pragma unroll
    for (int j = 0; j < 4; ++j) {
      b[j][0] = *(const bf16x8*)(sB + j * 1024);
      b[j][1] = *(const bf16x8*)(sB + 8192 + j * 1024);
    }
    asm volatile("s_waitcnt lgkmcnt(0)" ::: "memory");  // frag reads done
    __builtin_amdgcn_sched_barrier(0);
    __builtin_amdgcn_s_barrier();  // all reads done; next STAGE may overwrite

    __builtin_amdgcn_s_setprio(1);
#pragma unroll
    for (int i = 0; i < 4; ++i)
#pragma unroll
      for (int j = 0; j < 4; ++j) {
        acc[i][j] = __builtin_amdgcn_mfma_f32_16x16x32_bf16(a[i][0], b[j][0], acc[i][j], 0, 0, 0);
        acc[i][j] = __builtin_amdgcn_mfma_f32_16x16x32_bf16(a[i][0], b[j][1], acc[i][j], 0, 0, 0);
        acc[i][j] = __builtin_amdgcn_mfma_f32_16x16x32_bf16(a[i][1], b[j][0], acc[i][j], 0, 0, 0);
      }
    __builtin_amdgcn_s_setprio(0);
  }
#undef STAGE

  // epilogue: C/D layout: col = lane&15, row = (lane>>4)*4 + reg
  const int r0 = bm + wr * 64 + ((l >> 4) << 2);
  const int c0 = bn + wc * 64 + (l & 15);
#pragma unroll
  for (int j = 0; j < 4; ++j) {
    const int col = c0 + j * 16;
    const float bv = bias[col];
#pragma unroll
    for (int i = 0; i < 4; ++i) {
      const int row = r0 + i * 16;
#pragma unroll
      for (int r = 0; r < 4; ++r) {
        float v = acc[i][j][r] + bv;
        if (RELU) v = fmaxf(v, 0.f);
        C[(size_t)(row + r) * N + col] = v;
      }
    }
  }
}

// ---------------- L3: 256x256 / 8-wave mgemm + fused pool, single-buffer --
// LDS 64KB single buffer: [A-hi 16K | A-lo 16K | B-hi 16K | B-lo 16K].
// Pipeline per K-step: vmcnt(0)+bar (staged) -> ds_read 24 frags ->
// lgkm(0)+bar (buffer free) -> STAGE(kt+1) async -> 96 MFMA (loads land
// underneath). 2 blocks/CU at 64KB.
__global__ __launch_bounds__(512, 2) void k_mgemm3(
    const unsigned short* __restrict__ Ah, const unsigned short* __restrict__ Al,
    const unsigned short* __restrict__ Bh_a, const unsigned short* __restrict__ Bl_a,
    const unsigned short* __restrict__ Bh_b, const unsigned short* __restrict__ Bl_b,
    const float* __restrict__ bias_a, const float* __restrict__ bias_b,
    const int* __restrict__ bs, const int* __restrict__ bt,
    float* __restrict__ P2, int N, int K) {
  __shared__ char smem[65536];
  const int t = threadIdx.x;
  const int w = t >> 6, l = t & 63;
  const int bid = blockIdx.x;
  const int bn_ = bid & 7, bm_ = bid >> 3;
  const int bm = bm_ * 256, bn = bn_ * 256;
  const bool sec = bm >= NNP2;            // 10240 % 256 == 0: no straddle
  const unsigned short* Bh = sec ? Bh_b : Bh_a;
  const unsigned short* Bl = sec ? Bl_b : Bl_a;
  const float* bias = sec ? bias_b : bias_a;
  const int* batch = sec ? bt : bs;
  float* P2g = P2 + (sec ? (size_t)NG * 2048 : 0);
  const int lbase = bm - (sec ? NNP2 : 0);  // branch-local row base

  const int wr = w >> 2, wc = w & 3;

  f32x4 acc[8][4] = {};

  // staging: part = w>>1 (0:Ahi 1:Alo 2:Bhi 3:Blo); half = w&1 (rows +0/+128)
  const int part = w >> 1, half = w & 1;
  const unsigned short* gmat = (part == 0) ? Ah : (part == 1) ? Al
                             : (part == 2) ? Bh : Bl;
  const int rb = ((part < 2) ? bm : bn) + half * 128;
  const unsigned short* gsbase = gmat + (size_t)(rb + (l & 15)) * K + ((l >> 4) * 8);
  const int sdoff = part * 16384 + half * 8192 + l * 16;

  const int saoff = (wr * 8) * 1024 + l * 16;          // A-hi; A-lo +16384
  const int sboff = 32768 + (wc * 4) * 1024 + l * 16;  // B-hi; B-lo +16384

  const int nt = K >> 5;

#define STAGE3(kt)                                                           \
  {                                                                          \
    _Pragma("unroll") for (int c = 0; c < 8; ++c)                            \
        GLOAD_LDS16(gsbase + (size_t)c * 16 * K + ((kt) << 5),               \
                    smem + sdoff + c * 1024);                                \
  }

  STAGE3(0)

  for (int kt = 0; kt < nt; ++kt) {
    asm volatile("s_waitcnt vmcnt(0)" ::: "memory");  // tile kt landed
    __builtin_amdgcn_sched_barrier(0);
    __builtin_amdgcn_s_barrier();

    bf16x8 bh[4], blo[4], ah[8], alo[8];
#pragma unroll
    for (int j = 0; j < 4; ++j) {
      bh[j]  = *(const bf16x8*)(smem + sboff + j * 1024);
      blo[j] = *(const bf16x8*)(smem + sboff + 16384 + j * 1024);
    }
#pragma unroll
    for (int i = 0; i < 8; ++i) {
      ah[i]  = *(const bf16x8*)(smem + saoff + i * 1024);
      alo[i] = *(const bf16x8*)(smem + saoff + 16384 + i * 1024);
    }
    asm volatile("s_waitcnt lgkmcnt(0)" ::: "memory");  // frags in regs
    __builtin_amdgcn_sched_barrier(0);
    __builtin_amdgcn_s_barrier();  // all waves done reading -> buffer free

    if (kt + 1 < nt) STAGE3(kt + 1)  // async loads fly under the MFMAs

    __builtin_amdgcn_s_setprio(1);
#pragma unroll
    for (int i = 0; i < 8; ++i)
#pragma unroll
      for (int j = 0; j < 4; ++j) {
        acc[i][j] = __builtin_amdgcn_mfma_f32_16x16x32_bf16(ah[i], bh[j], acc[i][j], 0, 0, 0);
        acc[i][j] = __builtin_amdgcn_mfma_f32_16x16x32_bf16(ah[i], blo[j], acc[i][j], 0, 0, 0);
        acc[i][j] = __builtin_amdgcn_mfma_f32_16x16x32_bf16(alo[i], bh[j], acc[i][j], 0, 0, 0);
      }
    __builtin_amdgcn_s_setprio(0);
  }
#undef STAGE3

  // epilogue: bias + ReLU + segmented atomicMax pool (no C store)
  const int r0l = lbase + wr * 128 + ((l >> 4) << 2);
  const int c0 = bn + wc * 64 + (l & 15);
#pragma unroll
  for (int j = 0; j < 4; ++j) {
    const int col = c0 + j * 16;
    const float bv = bias[col];
    float* Pcol = P2g + col;
#pragma unroll
    for (int i = 0; i < 8; ++i) {
      const int rl = r0l + i * 16;
      if (rl >= NN) continue;
      float v0 = fmaxf(acc[i][j][0] + bv, 0.f);
      float v1 = fmaxf(acc[i][j][1] + bv, 0.f);
      float v2 = fmaxf(acc[i][j][2] + bv, 0.f);
      float v3 = fmaxf(acc[i][j][3] + bv, 0.f);
      if (rl + 3 < NN) {
        int g0i = batch[rl], g3i = batch[rl + 3];
        if (g0i == g3i) {
          float m = fmaxf(fmaxf(v0, v1), fmaxf(v2, v3));
          atomicMax((int*)(Pcol + (size_t)g0i * 2048), __float_as_int(m));
        } else {
          int g1i = batch[rl + 1], g2i = batch[rl + 2];
          atomicMax((int*)(Pcol + (size_t)g0i * 2048), __float_as_int(v0));
          atomicMax((int*)(Pcol + (size_t)g1i * 2048), __float_as_int(v1));
          atomicMax((int*)(Pcol + (size_t)g2i * 2048), __float_as_int(v2));
          atomicMax((int*)(Pcol + (size_t)g3i * 2048), __float_as_int(v3));
        }
      } else {
        float vv[4] = {v0, v1, v2, v3};
        for (int r = 0; r < 4; ++r) {
          if (rl + r < NN) {
            int g = batch[rl + r];
            atomicMax((int*)(Pcol + (size_t)g * 2048), __float_as_int(vv[r]));
          }
        }
      }
    }
  }
}

// ---------------- split-K fp32 GEMM for the tiny head (M=128) -------------
__global__ __launch_bounds__(256) void k_gemm_sk(
    const float* __restrict__ A, const float* __restrict__ A2,
    const float* __restrict__ B,
    float* __restrict__ PART, int M, int N, int K, int KS) {
  __shared__ float As[32][64];
  __shared__ float Bs[32][64];

  int t = threadIdx.x;
  int tx = t & 15, ty = t >> 4;
  int bm = blockIdx.y * 64, bn = blockIdx.x * 64;
  int kbeg = blockIdx.z * KS, kend = kbeg + KS;

  float acc[4][4] = {};

  int arow0 = t >> 3;
  int ak4 = (t & 7) * 4;
  int brow0 = t >> 4;
  int bn4 = (t & 15) * 4;
  const bool n4al = (N & 3) == 0;

  for (int k0 = kbeg; k0 < kend; k0 += 32) {
#pragma unroll
    for (int c = 0; c < 2; ++c) {
      int row = arow0 + c * 32;
      int gr = bm + row;
      float4 v = make_float4(0.f, 0.f, 0.f, 0.f);
      if (gr < M) {
        v = *(const float4*)&A[(size_t)gr * K + k0 + ak4];
        if (A2) {
          float4 v2 = *(const float4*)&A2[(size_t)gr * K + k0 + ak4];
          v.x += v2.x; v.y += v2.y; v.z += v2.z; v.w += v2.w;
        }
      }
      As[ak4 + 0][row] = v.x;
      As[ak4 + 1][row] = v.y;
      As[ak4 + 2][row] = v.z;
      As[ak4 + 3][row] = v.w;
    }
#pragma unroll
    for (int c = 0; c < 2; ++c) {
      int row = brow0 + c * 16;
      int gc = bn + bn4;
      const float* bp = &B[(size_t)(k0 + row) * N + gc];
      float4 v;
      if (n4al && gc + 3 < N) {
        v = *(const float4*)bp;
      } else {
        v = make_float4(0.f, 0.f, 0.f, 0.f);
        if (gc < N) v.x = bp[0];
        if (gc + 1 < N) v.y = bp[1];
        if (gc + 2 < N) v.z = bp[2];
        if (gc + 3 < N) v.w = bp[3];
      }
      *(float4*)&Bs[row][bn4] = v;
    }
    __syncthreads();

#pragma unroll
    for (int kk = 0; kk < 32; ++kk) {
      float4 a = *(const float4*)&As[kk][ty * 4];
      float4 b = *(const float4*)&Bs[kk][tx * 4];
      float av[4] = {a.x, a.y, a.z, a.w};
      float bv[4] = {b.x, b.y, b.z, b.w};
#pragma unroll
      for (int i = 0; i < 4; ++i)
#pragma unroll
        for (int j = 0; j < 4; ++j)
          acc[i][j] = fmaf(av[i], bv[j], acc[i][j]);
    }
    __syncthreads();
  }

  float* P = PART + (size_t)blockIdx.z * M * N;
  int r0 = bm + ty * 4, c0 = bn + tx * 4;
#pragma unroll
  for (int i = 0; i < 4; ++i) {
    int r = r0 + i;
    if (r < M) {
#pragma unroll
      for (int j = 0; j < 4; ++j) {
        int c = c0 + j;
        if (c < N) P[(size_t)r * N + c] = acc[i][j];
      }
    }
  }
}

// reduce SK partials + bias (+relu or logits+sigmoid)
template <bool SIG>
__global__ void k_reduce(const float* __restrict__ PART,
                         const float* __restrict__ bias,
                         float* __restrict__ C, float* __restrict__ C2,
                         int MN, int N, int SK) {
  int i = blockIdx.x * blockDim.x + threadIdx.x;
  if (i >= MN) return;
  float s = 0.f;
  for (int z = 0; z < SK; ++z) s += PART[(size_t)z * MN + i];
  s += bias[i % N];
  if (SIG) {
    C[i] = s;
    C2[i] = 1.0f / (1.0f + __expf(-s));
  } else {
    C[i] = fmaxf(s, 0.f);
  }
}

// ---------------- entry ----------------

extern "C" void kernel_launch(void* const* d_in, const int* in_sizes, int n_in,
                              void* d_out, int out_size, void* d_ws, size_t ws_size,
                              hipStream_t stream) {
  const float* x_s = (const float*)d_in[0];
  const float* x_t = (const float*)d_in[1];
  const int* ei_s = (const int*)d_in[2];
  const int* ei_t = (const int*)d_in[3];
  const int* xs_batch = (const int*)d_in[4];
  const int* xt_batch = (const int*)d_in[5];
  const float* W_enc1 = (const float*)d_in[6];
  const float* b_enc1 = (const float*)d_in[7];
  const float* W_enc2 = (const float*)d_in[8];
  const float* b_enc2 = (const float*)d_in[9];
  const float* W_r1g1 = (const float*)d_in[10];
  const float* b_r1g1 = (const float*)d_in[11];
  const float* W_r1g2 = (const float*)d_in[12];
  const float* b_r1g2 = (const float*)d_in[13];
  const float* W_r2g1 = (const float*)d_in[14];
  const float* b_r2g1 = (const float*)d_in[15];
  const float* W_r2g2 = (const float*)d_in[16];
  const float* b_r2g2 = (const float*)d_in[17];
  const float* W_l1 = (const float*)d_in[18];
  const float* b_l1 = (const float*)d_in[19];
  const float* W_l2 = (const float*)d_in[20];
  const float* b_l2 = (const float*)d_in[21];

  float* out = (float*)d_out;

  char* ws = (char*)d_ws;
  size_t off = 0;
  auto carve = [&](size_t bytes) {
    char* p = ws + off;
    off = (off + bytes + 255) & ~(size_t)255;
    return p;
  };
  // ACT: L1 out (MT2 x 512 f32) then L2 out (MT2 x 1024 f32). L3 output is
  // never materialized (fused atomic pool).
  float* ACT = (float*)carve((size_t)MT2 * 1024 * 4);
  unsigned short* Ah = (unsigned short*)carve((size_t)MT2 * 1024 * 2);
  unsigned short* Al = (unsigned short*)carve((size_t)MT2 * 1024 * 2);
  // weight splits (transposed [N][K] bf16 hi/lo)
  unsigned short* W1h_a = (unsigned short*)carve((size_t)512 * 128 * 2);
  unsigned short* W1l_a = (unsigned short*)carve((size_t)512 * 128 * 2);
  unsigned short* W1h_b = (unsigned short*)carve((size_t)512 * 128 * 2);
  unsigned short* W1l_b = (unsigned short*)carve((size_t)512 * 128 * 2);
  unsigned short* W2h_a = (unsigned short*)carve((size_t)1024 * 512 * 2);
  unsigned short* W2l_a = (unsigned short*)carve((size_t)1024 * 512 * 2);
  unsigned short* W2h_b = (unsigned short*)carve((size_t)1024 * 512 * 2);
  unsigned short* W2l_b = (unsigned short*)carve((size_t)1024 * 512 * 2);
  unsigned short* W3h_a = (unsigned short*)carve((size_t)2048 * 1024 * 2);
  unsigned short* W3l_a = (unsigned short*)carve((size_t)2048 * 1024 * 2);
  unsigned short* W3h_b = (unsigned short*)carve((size_t)2048 * 1024 * 2);
  unsigned short* W3l_b = (unsigned short*)carve((size_t)2048 * 1024 * 2);
  float* P2   = (float*)carve((size_t)2 * NG * 2048 * 4);   // pooled, both branches
  float* ZZ   = (float*)carve((size_t)NG * 1024 * 4);
  float* PART = (float*)carve((size_t)16 * NG * 1024 * 4);  // split-K partials
  float* dinv = (float*)carve((size_t)MT2 * 4);
  int* cnt     = (int*)carve((size_t)MT2 * 4);
  int* row_ptr = (int*)carve((size_t)(MT2 + 1) * 4);
  int* cursor  = (int*)carve((size_t)MT2 * 4);
  int* csr_src = (int*)carve((size_t)2 * NE * 4);
  (void)ws_size; (void)n_in; (void)in_sizes; (void)out_size;

  // weight transpose+split, both branches batched via grid.z
  k_wsplit2<<<dim3(512 / 32, 128 / 32, 2), 256, 0, stream>>>(
      W_enc1, W1h_a, W1l_a, W_enc2, W1h_b, W1l_b, 128, 512);
  k_wsplit2<<<dim3(1024 / 32, 512 / 32, 2), 256, 0, stream>>>(
      W_r1g1, W2h_a, W2l_a, W_r2g1, W2h_b, W2l_b, 512, 1024);
  k_wsplit2<<<dim3(2048 / 32, 1024 / 32, 2), 256, 0, stream>>>(
      W_r1g2, W3h_a, W3l_a, W_r2g2, W3h_b, W3l_b, 1024, 2048);

  // batched CSR build
  hipMemsetAsync(cnt, 0, (size_t)MT2 * 4, stream);
  k_count2<<<(2 * NE + 255) / 256, 256, 0, stream>>>(ei_s, ei_t, cnt);
  k_scan<<<1, 256, 0, stream>>>(cnt, row_ptr, cursor, dinv);
  k_scatter2<<<(2 * NE + 255) / 256, 256, 0, stream>>>(ei_s, ei_t, cursor, csr_src);

  // L1: agg (dual input) [F=128] -> GEMM M=MT2, N=512, K=128 (no relu)
  k_agg_x<4, true><<<NB2 * 4, 256, 0, stream>>>(
      x_s, x_t, Ah, Al, row_ptr, csr_src, dinv);
  k_mgemm<false, 4><<<4 * (MT2 / 128), 256, 0, stream>>>(
      Ah, Al, W1h_a, W1l_a, W1h_b, W1l_b, b_enc1, b_enc2, ACT, 512, 128);

  // L2: agg [F=512] -> relu GEMM M=MT2, N=1024, K=512
  k_agg_x<16, false><<<NB2 * 16, 256, 0, stream>>>(
      ACT, nullptr, Ah, Al, row_ptr, csr_src, dinv);
  k_mgemm<true, 8><<<8 * (MT2 / 128), 256, 0, stream>>>(
      Ah, Al, W2h_a, W2l_a, W2h_b, W2l_b, b_r1g1, b_r2g1, ACT, 1024, 512);

  // L3: agg [F=1024] -> merged 256^2 GEMM with fused atomicMax pool
  k_agg_x<32, false><<<NB2 * 32, 256, 0, stream>>>(
      ACT, nullptr, Ah, Al, row_ptr, csr_src, dinv);
  hipMemsetAsync(P2, 0, (size_t)2 * NG * 2048 * 4, stream);
  k_mgemm3<<<8 * (MT2 / 256), 512, 0, stream>>>(
      Ah, Al, W3h_a, W3l_a, W3h_b, W3l_b, b_r1g2, b_r2g2,
      xs_batch, xt_batch, P2, 2048, 1024);

  // MLP head, split-K fp32 (Z = P_s + P_t fused into A-load)
  k_gemm_sk<<<dim3(1024 / 64, 2, 16), 256, 0, stream>>>(
      P2, P2 + (size_t)NG * 2048, W_l1, PART, NG, 1024, 2048, 128);
  k_reduce<false><<<(NG * 1024 + 255) / 256, 256, 0, stream>>>(
      PART, b_l1, ZZ, nullptr, NG * 1024, 1024, 16);

  const int OUTN = 1317;
  k_gemm_sk<<<dim3((OUTN + 63) / 64, 2, 8), 256, 0, stream>>>(
      ZZ, nullptr, W_l2, PART, NG, OUTN, 1024, 128);
  k_reduce<true><<<(NG * OUTN + 255) / 256, 256, 0, stream>>>(
      PART, b_l2, out, out + (size_t)NG * OUTN, NG * OUTN, OUTN, 8);
}

// Round 16
// 768.354 us; speedup vs baseline: 1.0561x; 1.0162x over previous
//
#include <hip/hip_runtime.h>
#include <cstdint>
#include <cstddef>

// ---------------------------------------------------------------------------
// SSLModel: dual-branch GCN + global max pool + MLP head.
// Round 16: exact revert to R12 (best measured: 770.6 us).
// Post-mortem conclusion: split-bf16 MFMA GEMM is LDS-bandwidth-structural-
// bound (~256B LDS read per MFMA vs ~112B/clk/CU at 0.82 MFMA/clk demand ->
// ~40-45% MfmaUtil ceiling); 5 schedule/geometry A/B experiments (counted
// vmcnt, XCD swizzle, lo-bypass, barrier reorder, single-buffer pipeline)
// all landed 355-400us. R12's 256^2 + dbuf + fused atomicMax pool is the
// best point in the family.
// ---------------------------------------------------------------------------

#define NN 10000      // nodes per graph-batch
#define NNP2 10240    // padded to 256 (40 tiles)
#define MT2 20480     // 2*NNP2 merged rows
#define NB2 640       // MT2/32 node-blocks
#define NE 160000     // edges per branch
#define NG 128        // graphs per branch

typedef short bf16x8 __attribute__((ext_vector_type(8)));
typedef float f32x4 __attribute__((ext_vector_type(4)));

__device__ __forceinline__ unsigned short f2bf(float x) {
  unsigned u = __float_as_uint(x);
  u += 0x7FFFu + ((u >> 16) & 1u);   // RNE (finite inputs)
  return (unsigned short)(u >> 16);
}
__device__ __forceinline__ float bf2f(unsigned short h) {
  return __uint_as_float(((unsigned)h) << 16);
}
__device__ __forceinline__ void fma4(float4& d, float s, const float4& u) {
  d.x = fmaf(s, u.x, d.x);
  d.y = fmaf(s, u.y, d.y);
  d.z = fmaf(s, u.z, d.z);
  d.w = fmaf(s, u.w, d.w);
}

#define GLOAD_LDS16(gp, lp)                                                  \
  __builtin_amdgcn_global_load_lds(                                          \
      (const __attribute__((address_space(1))) void*)(gp),                   \
      (__attribute__((address_space(3))) void*)(lp), 16, 0, 0)

// ---------------- CSR build (both branches batched) ----------------

__global__ void k_count2(const int* __restrict__ eis, const int* __restrict__ eit,
                         int* __restrict__ cnt) {
  int i = blockIdx.x * blockDim.x + threadIdx.x;
  if (i >= 2 * NE) return;
  int d;
  if (i < NE) d = eis[NE + i];
  else        d = eit[NE + (i - NE)] + NNP2;
  atomicAdd(&cnt[d], 1);
}

// scan + dinv (single block, 256 thr, n = MT2)
__global__ void k_scan(const int* __restrict__ cnt, int* __restrict__ row_ptr,
                       int* __restrict__ cursor, float* __restrict__ dinv) {
  __shared__ int part[256];
  __shared__ int partex[257];
  int t = threadIdx.x;
  const int n = MT2;
  const int CH = n / 256;
  int base = t * CH;
  int s = 0;
  for (int i = 0; i < CH; ++i) s += cnt[base + i];
  part[t] = s;
  __syncthreads();
  if (t == 0) {
    int acc = 0;
    for (int i = 0; i < 256; ++i) { partex[i] = acc; acc += part[i]; }
    partex[256] = acc;
  }
  __syncthreads();
  int acc = partex[t];
  for (int i = 0; i < CH; ++i) {
    int idx = base + i;
    row_ptr[idx] = acc;
    cursor[idx]  = acc;
    dinv[idx] = rsqrtf((float)cnt[idx] + 1.0f);
    acc += cnt[idx];
  }
  if (t == 255) row_ptr[n] = partex[256];
}

// src-only CSR (weight recomputed in agg), grouped by dst_global
__global__ void k_scatter2(const int* __restrict__ eis, const int* __restrict__ eit,
                           int* __restrict__ cursor, int* __restrict__ csr_src) {
  int i = blockIdx.x * blockDim.x + threadIdx.x;
  if (i >= 2 * NE) return;
  int s, d;
  if (i < NE) { s = eis[i]; d = eis[NE + i]; }
  else { int j = i - NE; s = eit[j] + NNP2; d = eit[NE + j] + NNP2; }
  int pos = atomicAdd(&cursor[d], 1);
  csr_src[pos] = s;
}

// ---------------- XCD-pinned chunk-column aggregate + bf16 split -----------
template <int NCH, bool DUAL>
__global__ __launch_bounds__(256) void k_agg_x(
    const float* __restrict__ in0, const float* __restrict__ in1,
    unsigned short* __restrict__ Ah, unsigned short* __restrict__ Al,
    const int* __restrict__ row_ptr, const int* __restrict__ csr_src,
    const float* __restrict__ dinv) {
  constexpr int F4TOT = NCH * 8;
  const int bid = blockIdx.x;
  const int xcd = bid & 7;
  const int seq = bid >> 3;
  int chunk, nodeblk;
  if constexpr (NCH >= 8) {
    int phase = seq / NB2;
    nodeblk = seq - phase * NB2;
    chunk = phase * 8 + xcd;
  } else {  // NCH == 4: two XCDs share a chunk (even/odd node-blocks)
    chunk = xcd >> 1;
    nodeblk = (seq << 1) | (xcd & 1);
  }
  const int t = threadIdx.x;
  const int node = nodeblk * 32 + (t >> 3);
  const int f4 = chunk * 8 + (t & 7);

  size_t o = (size_t)node * F4TOT + f4;
  ushort4* oh = (ushort4*)Ah + o;
  ushort4* ol = (ushort4*)Al + o;
  int local = (node < NNP2) ? node : (node - NNP2);
  if (local >= NN) {   // pad row
    *oh = make_ushort4(0, 0, 0, 0);
    *ol = make_ushort4(0, 0, 0, 0);
    return;
  }
  const float4* i0 = (const float4*)in0;
  const float4* i1 = (const float4*)in1;
  auto rowp = [&](int g) -> const float4* {
    if (DUAL)
      return (g < NNP2) ? (i0 + (size_t)g * F4TOT)
                        : (i1 + (size_t)(g - NNP2) * F4TOT);
    return i0 + (size_t)g * F4TOT;
  };

  float di = dinv[node];
  float sw = di * di;
  float4 v = rowp(node)[f4];
  float4 acc;
  acc.x = sw * v.x; acc.y = sw * v.y; acc.z = sw * v.z; acc.w = sw * v.w;

  const int e0 = row_ptr[node], e1 = row_ptr[node + 1];
  int e = e0;
  for (; e + 4 <= e1; e += 4) {
    int s0 = csr_src[e], s1 = csr_src[e + 1];
    int s2 = csr_src[e + 2], s3 = csr_src[e + 3];
    float4 u0 = rowp(s0)[f4];
    float4 u1 = rowp(s1)[f4];
    float4 u2 = rowp(s2)[f4];
    float4 u3 = rowp(s3)[f4];
    float w0 = dinv[s0] * di, w1 = dinv[s1] * di;
    float w2 = dinv[s2] * di, w3 = dinv[s3] * di;
    fma4(acc, w0, u0);
    fma4(acc, w1, u1);
    fma4(acc, w2, u2);
    fma4(acc, w3, u3);
  }
  for (; e < e1; ++e) {
    int s = csr_src[e];
    float4 u = rowp(s)[f4];
    fma4(acc, dinv[s] * di, u);
  }

  ushort4 h, l;
  h.x = f2bf(acc.x); l.x = f2bf(acc.x - bf2f(h.x));
  h.y = f2bf(acc.y); l.y = f2bf(acc.y - bf2f(h.y));
  h.z = f2bf(acc.z); l.z = f2bf(acc.z - bf2f(h.z));
  h.w = f2bf(acc.w); l.w = f2bf(acc.w - bf2f(h.w));
  *oh = h;
  *ol = l;
}

// ---------------- weight transpose + split, 2 weight sets batched --------
__global__ __launch_bounds__(256) void k_wsplit2(
    const float* __restrict__ W0, unsigned short* __restrict__ H0,
    unsigned short* __restrict__ L0,
    const float* __restrict__ W1, unsigned short* __restrict__ H1,
    unsigned short* __restrict__ L1, int K, int N) {
  const float* W = blockIdx.z ? W1 : W0;
  unsigned short* Ht = blockIdx.z ? H1 : H0;
  unsigned short* Lt = blockIdx.z ? L1 : L0;
  __shared__ float tile[32][33];
  int nb = blockIdx.x * 32, kb = blockIdx.y * 32;
  int tx = threadIdx.x & 31, ty = threadIdx.x >> 5;
#pragma unroll
  for (int r = ty; r < 32; r += 8)
    tile[r][tx] = W[(size_t)(kb + r) * N + nb + tx];
  __syncthreads();
#pragma unroll
  for (int r = ty; r < 32; r += 8) {
    float x = tile[tx][r];  // = W[kb+tx][nb+r]
    unsigned short h = f2bf(x);
    unsigned short lo = f2bf(x - bf2f(h));
    size_t o = (size_t)(nb + r) * K + kb + tx;
    Ht[o] = h;
    Lt[o] = lo;
  }
}

// ---------------- split-bf16 MFMA GEMM 128x128 (R12 schedule) -------------
template <bool RELU, int GX>
__global__ __launch_bounds__(256) void k_mgemm(
    const unsigned short* __restrict__ Ah, const unsigned short* __restrict__ Al,
    const unsigned short* __restrict__ Bh_a, const unsigned short* __restrict__ Bl_a,
    const unsigned short* __restrict__ Bh_b, const unsigned short* __restrict__ Bl_b,
    const float* __restrict__ bias_a, const float* __restrict__ bias_b,
    float* __restrict__ C, int N, int K) {
  __shared__ char smem[65536];  // 2 x [Ah|Al|Bh|Bl] x 8KiB
  const int t = threadIdx.x;
  const int w = t >> 6, l = t & 63;

  const int bid = blockIdx.x;
  const int bn_ = bid & (GX - 1), bm_ = bid / GX;
  const int bm = bm_ * 128, bn = bn_ * 128;
  const bool sec = bm >= NNP2;
  const unsigned short* Bh = sec ? Bh_b : Bh_a;
  const unsigned short* Bl = sec ? Bl_b : Bl_a;
  const float* bias = sec ? bias_b : bias_a;

  const int wr = w >> 1, wc = w & 1;

  f32x4 acc[4][4] = {};

  // staging: wave w owns matrix w entirely (8 x 1KiB chunks)
  const unsigned short* g0 = (w == 0) ? Ah : (w == 1) ? Al : (w == 2) ? Bh : Bl;
  const int rb = (w < 2) ? bm : bn;
  const unsigned short* gbase = g0 + (size_t)(rb + (l & 15)) * K + ((l >> 4) * 8);
  const int sdoff = w * 8192 + l * 16;
  const int saoff = wr * 4096 + l * 16;          // A-hi frags; A-lo at +8192
  const int sboff = 16384 + wc * 4096 + l * 16;  // B-hi frags; B-lo at +8192

  const int nt = K >> 5;

#define STAGE(kt, b)                                                         \
  {                                                                          \
    const unsigned short* gk = gbase + ((kt) << 5);                          \
    char* sd = smem + (b)*32768 + sdoff;                                     \
    _Pragma("unroll") for (int s = 0; s < 8; ++s)                            \
        GLOAD_LDS16(gk + (size_t)s * 16 * K, sd + s * 1024);                 \
  }

  STAGE(0, 0)

  for (int kt = 0; kt < nt; ++kt) {
    const int cur = kt & 1;
    if (kt + 1 < nt) {
      STAGE(kt + 1, cur ^ 1)
      asm volatile("s_waitcnt vmcnt(8)" ::: "memory");  // tile kt landed
    } else {
      asm volatile("s_waitcnt vmcnt(0)" ::: "memory");
    }
    __builtin_amdgcn_sched_barrier(0);
    __builtin_amdgcn_s_barrier();  // collective: buf[cur] fully staged

    const char* sA = smem + cur * 32768 + saoff;
    const char* sB = smem + cur * 32768 + sboff;
    bf16x8 a[4][2], b[4][2];
#pragma unroll
    for (int i = 0; i < 4; ++i) {
      a[i][0] = *(const bf16x8*)(sA + i * 1024);
      a[i][1] = *(const bf16x8*)(sA + 8192 + i * 1024);
    }
#pragma unroll
    for (int j = 0; j < 4; ++j) {
      b[j][0] = *(const bf16x8*)(sB + j * 1024);
      b[j][1] = *(const bf16x8*)(sB + 8192 + j * 1024);
    }
    asm volatile("s_waitcnt lgkmcnt(0)" ::: "memory");  // frag reads done
    __builtin_amdgcn_sched_barrier(0);
    __builtin_amdgcn_s_barrier();  // all reads done; next STAGE may overwrite

    __builtin_amdgcn_s_setprio(1);
#pragma unroll
    for (int i = 0; i < 4; ++i)
#pragma unroll
      for (int j = 0; j < 4; ++j) {
        acc[i][j] = __builtin_amdgcn_mfma_f32_16x16x32_bf16(a[i][0], b[j][0], acc[i][j], 0, 0, 0);
        acc[i][j] = __builtin_amdgcn_mfma_f32_16x16x32_bf16(a[i][0], b[j][1], acc[i][j], 0, 0, 0);
        acc[i][j] = __builtin_amdgcn_mfma_f32_16x16x32_bf16(a[i][1], b[j][0], acc[i][j], 0, 0, 0);
      }
    __builtin_amdgcn_s_setprio(0);
  }
#undef STAGE

  // epilogue: C/D layout: col = lane&15, row = (lane>>4)*4 + reg
  const int r0 = bm + wr * 64 + ((l >> 4) << 2);
  const int c0 = bn + wc * 64 + (l & 15);
#pragma unroll
  for (int j = 0; j < 4; ++j) {
    const int col = c0 + j * 16;
    const float bv = bias[col];
#pragma unroll
    for (int i = 0; i < 4; ++i) {
      const int row = r0 + i * 16;
#pragma unroll
      for (int r = 0; r < 4; ++r) {
        float v = acc[i][j][r] + bv;
        if (RELU) v = fmaxf(v, 0.f);
        C[(size_t)(row + r) * N + col] = v;
      }
    }
  }
}

// ---------------- L3: 256x256 / 8-wave mgemm + fused bias/ReLU/max-pool ----
// (R12 version: 2 x 64KB dbuf, counted vmcnt(8), lgkm-drain before MFMA,
//  atomicMax pool epilogue.)
__global__ __launch_bounds__(512, 2) void k_mgemm3(
    const unsigned short* __restrict__ Ah, const unsigned short* __restrict__ Al,
    const unsigned short* __restrict__ Bh_a, const unsigned short* __restrict__ Bl_a,
    const unsigned short* __restrict__ Bh_b, const unsigned short* __restrict__ Bl_b,
    const float* __restrict__ bias_a, const float* __restrict__ bias_b,
    const int* __restrict__ bs, const int* __restrict__ bt,
    float* __restrict__ P2, int N, int K) {
  __shared__ char smem[131072];
  const int t = threadIdx.x;
  const int w = t >> 6, l = t & 63;
  const int bid = blockIdx.x;
  const int bn_ = bid & 7, bm_ = bid >> 3;
  const int bm = bm_ * 256, bn = bn_ * 256;
  const bool sec = bm >= NNP2;            // 10240 % 256 == 0: no straddle
  const unsigned short* Bh = sec ? Bh_b : Bh_a;
  const unsigned short* Bl = sec ? Bl_b : Bl_a;
  const float* bias = sec ? bias_b : bias_a;
  const int* batch = sec ? bt : bs;
  float* P2g = P2 + (sec ? (size_t)NG * 2048 : 0);
  const int lbase = bm - (sec ? NNP2 : 0);  // branch-local row base

  const int wr = w >> 2, wc = w & 3;

  f32x4 acc[8][4] = {};

  // staging: part = w>>1 (0:Ahi 1:Alo 2:Bhi 3:Blo); half = w&1 (rows +0/+128)
  const int part = w >> 1, half = w & 1;
  const unsigned short* gmat = (part == 0) ? Ah : (part == 1) ? Al
                             : (part == 2) ? Bh : Bl;
  const int rb = ((part < 2) ? bm : bn) + half * 128;
  const unsigned short* gsbase = gmat + (size_t)(rb + (l & 15)) * K + ((l >> 4) * 8);
  const int sdoff = part * 16384 + half * 8192 + l * 16;

  const int saoff = (wr * 8) * 1024 + l * 16;          // A-hi; A-lo +16384
  const int sboff = 32768 + (wc * 4) * 1024 + l * 16;  // B-hi; B-lo +16384

  const int nt = K >> 5;

#define STAGE3(kt, b)                                                        \
  {                                                                          \
    _Pragma("unroll") for (int c = 0; c < 8; ++c)                            \
        GLOAD_LDS16(gsbase + (size_t)c * 16 * K + ((kt) << 5),               \
                    smem + (b)*65536 + sdoff + c * 1024);                    \
  }

  STAGE3(0, 0)

  for (int kt = 0; kt < nt; ++kt) {
    const int cur = kt & 1;
    if (kt + 1 < nt) {
      STAGE3(kt + 1, cur ^ 1)
      asm volatile("s_waitcnt vmcnt(8)" ::: "memory");
    } else {
      asm volatile("s_waitcnt vmcnt(0)" ::: "memory");
    }
    __builtin_amdgcn_sched_barrier(0);
    __builtin_amdgcn_s_barrier();

    const char* base = smem + cur * 65536;
    bf16x8 bh[4], blo[4], ah[8], alo[8];
#pragma unroll
    for (int j = 0; j < 4; ++j) {
      bh[j]  = *(const bf16x8*)(base + sboff + j * 1024);
      blo[j] = *(const bf16x8*)(base + sboff + 16384 + j * 1024);
    }
#pragma unroll
    for (int i = 0; i < 8; ++i) {
      ah[i]  = *(const bf16x8*)(base + saoff + i * 1024);
      alo[i] = *(const bf16x8*)(base + saoff + 16384 + i * 1024);
    }
    asm volatile("s_waitcnt lgkmcnt(0)" ::: "memory");
    __builtin_amdgcn_sched_barrier(0);
    __builtin_amdgcn_s_barrier();

    __builtin_amdgcn_s_setprio(1);
#pragma unroll
    for (int i = 0; i < 8; ++i)
#pragma unroll
      for (int j = 0; j < 4; ++j) {
        acc[i][j] = __builtin_amdgcn_mfma_f32_16x16x32_bf16(ah[i], bh[j], acc[i][j], 0, 0, 0);
        acc[i][j] = __builtin_amdgcn_mfma_f32_16x16x32_bf16(ah[i], blo[j], acc[i][j], 0, 0, 0);
        acc[i][j] = __builtin_amdgcn_mfma_f32_16x16x32_bf16(alo[i], bh[j], acc[i][j], 0, 0, 0);
      }
    __builtin_amdgcn_s_setprio(0);
  }
#undef STAGE3

  // epilogue: bias + ReLU + segmented atomicMax pool (no C store)
  const int r0l = lbase + wr * 128 + ((l >> 4) << 2);
  const int c0 = bn + wc * 64 + (l & 15);
#pragma unroll
  for (int j = 0; j < 4; ++j) {
    const int col = c0 + j * 16;
    const float bv = bias[col];
    float* Pcol = P2g + col;
#pragma unroll
    for (int i = 0; i < 8; ++i) {
      const int rl = r0l + i * 16;
      if (rl >= NN) continue;
      float v0 = fmaxf(acc[i][j][0] + bv, 0.f);
      float v1 = fmaxf(acc[i][j][1] + bv, 0.f);
      float v2 = fmaxf(acc[i][j][2] + bv, 0.f);
      float v3 = fmaxf(acc[i][j][3] + bv, 0.f);
      if (rl + 3 < NN) {
        int g0i = batch[rl], g3i = batch[rl + 3];
        if (g0i == g3i) {
          float m = fmaxf(fmaxf(v0, v1), fmaxf(v2, v3));
          atomicMax((int*)(Pcol + (size_t)g0i * 2048), __float_as_int(m));
        } else {
          int g1i = batch[rl + 1], g2i = batch[rl + 2];
          atomicMax((int*)(Pcol + (size_t)g0i * 2048), __float_as_int(v0));
          atomicMax((int*)(Pcol + (size_t)g1i * 2048), __float_as_int(v1));
          atomicMax((int*)(Pcol + (size_t)g2i * 2048), __float_as_int(v2));
          atomicMax((int*)(Pcol + (size_t)g3i * 2048), __float_as_int(v3));
        }
      } else {
        float vv[4] = {v0, v1, v2, v3};
        for (int r = 0; r < 4; ++r) {
          if (rl + r < NN) {
            int g = batch[rl + r];
            atomicMax((int*)(Pcol + (size_t)g * 2048), __float_as_int(vv[r]));
          }
        }
      }
    }
  }
}

// ---------------- split-K fp32 GEMM for the tiny head (M=128) -------------
__global__ __launch_bounds__(256) void k_gemm_sk(
    const float* __restrict__ A, const float* __restrict__ A2,
    const float* __restrict__ B,
    float* __restrict__ PART, int M, int N, int K, int KS) {
  __shared__ float As[32][64];
  __shared__ float Bs[32][64];

  int t = threadIdx.x;
  int tx = t & 15, ty = t >> 4;
  int bm = blockIdx.y * 64, bn = blockIdx.x * 64;
  int kbeg = blockIdx.z * KS, kend = kbeg + KS;

  float acc[4][4] = {};

  int arow0 = t >> 3;
  int ak4 = (t & 7) * 4;
  int brow0 = t >> 4;
  int bn4 = (t & 15) * 4;
  const bool n4al = (N & 3) == 0;

  for (int k0 = kbeg; k0 < kend; k0 += 32) {
#pragma unroll
    for (int c = 0; c < 2; ++c) {
      int row = arow0 + c * 32;
      int gr = bm + row;
      float4 v = make_float4(0.f, 0.f, 0.f, 0.f);
      if (gr < M) {
        v = *(const float4*)&A[(size_t)gr * K + k0 + ak4];
        if (A2) {
          float4 v2 = *(const float4*)&A2[(size_t)gr * K + k0 + ak4];
          v.x += v2.x; v.y += v2.y; v.z += v2.z; v.w += v2.w;
        }
      }
      As[ak4 + 0][row] = v.x;
      As[ak4 + 1][row] = v.y;
      As[ak4 + 2][row] = v.z;
      As[ak4 + 3][row] = v.w;
    }
#pragma unroll
    for (int c = 0; c < 2; ++c) {
      int row = brow0 + c * 16;
      int gc = bn + bn4;
      const float* bp = &B[(size_t)(k0 + row) * N + gc];
      float4 v;
      if (n4al && gc + 3 < N) {
        v = *(const float4*)bp;
      } else {
        v = make_float4(0.f, 0.f, 0.f, 0.f);
        if (gc < N) v.x = bp[0];
        if (gc + 1 < N) v.y = bp[1];
        if (gc + 2 < N) v.z = bp[2];
        if (gc + 3 < N) v.w = bp[3];
      }
      *(float4*)&Bs[row][bn4] = v;
    }
    __syncthreads();

#pragma unroll
    for (int kk = 0; kk < 32; ++kk) {
      float4 a = *(const float4*)&As[kk][ty * 4];
      float4 b = *(const float4*)&Bs[kk][tx * 4];
      float av[4] = {a.x, a.y, a.z, a.w};
      float bv[4] = {b.x, b.y, b.z, b.w};
#pragma unroll
      for (int i = 0; i < 4; ++i)
#pragma unroll
        for (int j = 0; j < 4; ++j)
          acc[i][j] = fmaf(av[i], bv[j], acc[i][j]);
    }
    __syncthreads();
  }

  float* P = PART + (size_t)blockIdx.z * M * N;
  int r0 = bm + ty * 4, c0 = bn + tx * 4;
#pragma unroll
  for (int i = 0; i < 4; ++i) {
    int r = r0 + i;
    if (r < M) {
#pragma unroll
      for (int j = 0; j < 4; ++j) {
        int c = c0 + j;
        if (c < N) P[(size_t)r * N + c] = acc[i][j];
      }
    }
  }
}

// reduce SK partials + bias (+relu or logits+sigmoid)
template <bool SIG>
__global__ void k_reduce(const float* __restrict__ PART,
                         const float* __restrict__ bias,
                         float* __restrict__ C, float* __restrict__ C2,
                         int MN, int N, int SK) {
  int i = blockIdx.x * blockDim.x + threadIdx.x;
  if (i >= MN) return;
  float s = 0.f;
  for (int z = 0; z < SK; ++z) s += PART[(size_t)z * MN + i];
  s += bias[i % N];
  if (SIG) {
    C[i] = s;
    C2[i] = 1.0f / (1.0f + __expf(-s));
  } else {
    C[i] = fmaxf(s, 0.f);
  }
}

// ---------------- entry ----------------

extern "C" void kernel_launch(void* const* d_in, const int* in_sizes, int n_in,
                              void* d_out, int out_size, void* d_ws, size_t ws_size,
                              hipStream_t stream) {
  const float* x_s = (const float*)d_in[0];
  const float* x_t = (const float*)d_in[1];
  const int* ei_s = (const int*)d_in[2];
  const int* ei_t = (const int*)d_in[3];
  const int* xs_batch = (const int*)d_in[4];
  const int* xt_batch = (const int*)d_in[5];
  const float* W_enc1 = (const float*)d_in[6];
  const float* b_enc1 = (const float*)d_in[7];
  const float* W_enc2 = (const float*)d_in[8];
  const float* b_enc2 = (const float*)d_in[9];
  const float* W_r1g1 = (const float*)d_in[10];
  const float* b_r1g1 = (const float*)d_in[11];
  const float* W_r1g2 = (const float*)d_in[12];
  const float* b_r1g2 = (const float*)d_in[13];
  const float* W_r2g1 = (const float*)d_in[14];
  const float* b_r2g1 = (const float*)d_in[15];
  const float* W_r2g2 = (const float*)d_in[16];
  const float* b_r2g2 = (const float*)d_in[17];
  const float* W_l1 = (const float*)d_in[18];
  const float* b_l1 = (const float*)d_in[19];
  const float* W_l2 = (const float*)d_in[20];
  const float* b_l2 = (const float*)d_in[21];

  float* out = (float*)d_out;

  char* ws = (char*)d_ws;
  size_t off = 0;
  auto carve = [&](size_t bytes) {
    char* p = ws + off;
    off = (off + bytes + 255) & ~(size_t)255;
    return p;
  };
  // ACT: L1 out (MT2 x 512 f32) then L2 out (MT2 x 1024 f32). L3 output is
  // never materialized (fused atomic pool).
  float* ACT = (float*)carve((size_t)MT2 * 1024 * 4);
  unsigned short* Ah = (unsigned short*)carve((size_t)MT2 * 1024 * 2);
  unsigned short* Al = (unsigned short*)carve((size_t)MT2 * 1024 * 2);
  // weight splits (transposed [N][K] bf16 hi/lo)
  unsigned short* W1h_a = (unsigned short*)carve((size_t)512 * 128 * 2);
  unsigned short* W1l_a = (unsigned short*)carve((size_t)512 * 128 * 2);
  unsigned short* W1h_b = (unsigned short*)carve((size_t)512 * 128 * 2);
  unsigned short* W1l_b = (unsigned short*)carve((size_t)512 * 128 * 2);
  unsigned short* W2h_a = (unsigned short*)carve((size_t)1024 * 512 * 2);
  unsigned short* W2l_a = (unsigned short*)carve((size_t)1024 * 512 * 2);
  unsigned short* W2h_b = (unsigned short*)carve((size_t)1024 * 512 * 2);
  unsigned short* W2l_b = (unsigned short*)carve((size_t)1024 * 512 * 2);
  unsigned short* W3h_a = (unsigned short*)carve((size_t)2048 * 1024 * 2);
  unsigned short* W3l_a = (unsigned short*)carve((size_t)2048 * 1024 * 2);
  unsigned short* W3h_b = (unsigned short*)carve((size_t)2048 * 1024 * 2);
  unsigned short* W3l_b = (unsigned short*)carve((size_t)2048 * 1024 * 2);
  float* P2   = (float*)carve((size_t)2 * NG * 2048 * 4);   // pooled, both branches
  float* ZZ   = (float*)carve((size_t)NG * 1024 * 4);
  float* PART = (float*)carve((size_t)16 * NG * 1024 * 4);  // split-K partials
  float* dinv = (float*)carve((size_t)MT2 * 4);
  int* cnt     = (int*)carve((size_t)MT2 * 4);
  int* row_ptr = (int*)carve((size_t)(MT2 + 1) * 4);
  int* cursor  = (int*)carve((size_t)MT2 * 4);
  int* csr_src = (int*)carve((size_t)2 * NE * 4);
  (void)ws_size; (void)n_in; (void)in_sizes; (void)out_size;

  // weight transpose+split, both branches batched via grid.z
  k_wsplit2<<<dim3(512 / 32, 128 / 32, 2), 256, 0, stream>>>(
      W_enc1, W1h_a, W1l_a, W_enc2, W1h_b, W1l_b, 128, 512);
  k_wsplit2<<<dim3(1024 / 32, 512 / 32, 2), 256, 0, stream>>>(
      W_r1g1, W2h_a, W2l_a, W_r2g1, W2h_b, W2l_b, 512, 1024);
  k_wsplit2<<<dim3(2048 / 32, 1024 / 32, 2), 256, 0, stream>>>(
      W_r1g2, W3h_a, W3l_a, W_r2g2, W3h_b, W3l_b, 1024, 2048);

  // batched CSR build
  hipMemsetAsync(cnt, 0, (size_t)MT2 * 4, stream);
  k_count2<<<(2 * NE + 255) / 256, 256, 0, stream>>>(ei_s, ei_t, cnt);
  k_scan<<<1, 256, 0, stream>>>(cnt, row_ptr, cursor, dinv);
  k_scatter2<<<(2 * NE + 255) / 256, 256, 0, stream>>>(ei_s, ei_t, cursor, csr_src);

  // L1: agg (dual input) [F=128] -> GEMM M=MT2, N=512, K=128 (no relu)
  k_agg_x<4, true><<<NB2 * 4, 256, 0, stream>>>(
      x_s, x_t, Ah, Al, row_ptr, csr_src, dinv);
  k_mgemm<false, 4><<<4 * (MT2 / 128), 256, 0, stream>>>(
      Ah, Al, W1h_a, W1l_a, W1h_b, W1l_b, b_enc1, b_enc2, ACT, 512, 128);

  // L2: agg [F=512] -> relu GEMM M=MT2, N=1024, K=512
  k_agg_x<16, false><<<NB2 * 16, 256, 0, stream>>>(
      ACT, nullptr, Ah, Al, row_ptr, csr_src, dinv);
  k_mgemm<true, 8><<<8 * (MT2 / 128), 256, 0, stream>>>(
      Ah, Al, W2h_a, W2l_a, W2h_b, W2l_b, b_r1g1, b_r2g1, ACT, 1024, 512);

  // L3: agg [F=1024] -> merged 256^2 GEMM with fused atomicMax pool
  k_agg_x<32, false><<<NB2 * 32, 256, 0, stream>>>(
      ACT, nullptr, Ah, Al, row_ptr, csr_src, dinv);
  hipMemsetAsync(P2, 0, (size_t)2 * NG * 2048 * 4, stream);
  k_mgemm3<<<8 * (MT2 / 256), 512, 0, stream>>>(
      Ah, Al, W3h_a, W3l_a, W3h_b, W3l_b, b_r1g2, b_r2g2,
      xs_batch, xt_batch, P2, 2048, 1024);

  // MLP head, split-K fp32 (Z = P_s + P_t fused into A-load)
  k_gemm_sk<<<dim3(1024 / 64, 2, 16), 256, 0, stream>>>(
      P2, P2 + (size_t)NG * 2048, W_l1, PART, NG, 1024, 2048, 128);
  k_reduce<false><<<(NG * 1024 + 255) / 256, 256, 0, stream>>>(
      PART, b_l1, ZZ, nullptr, NG * 1024, 1024, 16);

  const int OUTN = 1317;
  k_gemm_sk<<<dim3((OUTN + 63) / 64, 2, 8), 256, 0, stream>>>(
      ZZ, nullptr, W_l2, PART, NG, OUTN, 1024, 128);
  k_reduce<true><<<(NG * OUTN + 255) / 256, 256, 0, stream>>>(
      PART, b_l2, out, out + (size_t)NG * OUTN, NG * OUTN, OUTN, 8);
}

// Round 17
// 757.388 us; speedup vs baseline: 1.0714x; 1.0145x over previous
//
#include <hip/hip_runtime.h>
#include <cstdint>
#include <cstddef>

// ---------------------------------------------------------------------------
// SSLModel: dual-branch GCN + global max pool + MLP head.
// Round 17: R16/R12 base + bm-pinned XCD block mapping in both mgemm kernels:
// xcd = bid&7 owns bm-panels {xcd, xcd+8, ...} and walks all bn consecutively
// -> each 1MB A-panel stays in its XCD's L2 across the bn sweep (mgemm3
// FETCH showed 4.3x A over-fetch: 344MB vs 96MB unique). R7 tested bn-pinning
// (B-reuse, already cached -> null); bm-pinning targets the measured A dup.
// ---------------------------------------------------------------------------

#define NN 10000      // nodes per graph-batch
#define NNP2 10240    // padded to 256 (40 tiles)
#define MT2 20480     // 2*NNP2 merged rows
#define NB2 640       // MT2/32 node-blocks
#define NE 160000     // edges per branch
#define NG 128        // graphs per branch

typedef short bf16x8 __attribute__((ext_vector_type(8)));
typedef float f32x4 __attribute__((ext_vector_type(4)));

__device__ __forceinline__ unsigned short f2bf(float x) {
  unsigned u = __float_as_uint(x);
  u += 0x7FFFu + ((u >> 16) & 1u);   // RNE (finite inputs)
  return (unsigned short)(u >> 16);
}
__device__ __forceinline__ float bf2f(unsigned short h) {
  return __uint_as_float(((unsigned)h) << 16);
}
__device__ __forceinline__ void fma4(float4& d, float s, const float4& u) {
  d.x = fmaf(s, u.x, d.x);
  d.y = fmaf(s, u.y, d.y);
  d.z = fmaf(s, u.z, d.z);
  d.w = fmaf(s, u.w, d.w);
}

#define GLOAD_LDS16(gp, lp)                                                  \
  __builtin_amdgcn_global_load_lds(                                          \
      (const __attribute__((address_space(1))) void*)(gp),                   \
      (__attribute__((address_space(3))) void*)(lp), 16, 0, 0)

// ---------------- CSR build (both branches batched) ----------------

__global__ void k_count2(const int* __restrict__ eis, const int* __restrict__ eit,
                         int* __restrict__ cnt) {
  int i = blockIdx.x * blockDim.x + threadIdx.x;
  if (i >= 2 * NE) return;
  int d;
  if (i < NE) d = eis[NE + i];
  else        d = eit[NE + (i - NE)] + NNP2;
  atomicAdd(&cnt[d], 1);
}

// scan + dinv (single block, 256 thr, n = MT2)
__global__ void k_scan(const int* __restrict__ cnt, int* __restrict__ row_ptr,
                       int* __restrict__ cursor, float* __restrict__ dinv) {
  __shared__ int part[256];
  __shared__ int partex[257];
  int t = threadIdx.x;
  const int n = MT2;
  const int CH = n / 256;
  int base = t * CH;
  int s = 0;
  for (int i = 0; i < CH; ++i) s += cnt[base + i];
  part[t] = s;
  __syncthreads();
  if (t == 0) {
    int acc = 0;
    for (int i = 0; i < 256; ++i) { partex[i] = acc; acc += part[i]; }
    partex[256] = acc;
  }
  __syncthreads();
  int acc = partex[t];
  for (int i = 0; i < CH; ++i) {
    int idx = base + i;
    row_ptr[idx] = acc;
    cursor[idx]  = acc;
    dinv[idx] = rsqrtf((float)cnt[idx] + 1.0f);
    acc += cnt[idx];
  }
  if (t == 255) row_ptr[n] = partex[256];
}

// src-only CSR (weight recomputed in agg), grouped by dst_global
__global__ void k_scatter2(const int* __restrict__ eis, const int* __restrict__ eit,
                           int* __restrict__ cursor, int* __restrict__ csr_src) {
  int i = blockIdx.x * blockDim.x + threadIdx.x;
  if (i >= 2 * NE) return;
  int s, d;
  if (i < NE) { s = eis[i]; d = eis[NE + i]; }
  else { int j = i - NE; s = eit[j] + NNP2; d = eit[NE + j] + NNP2; }
  int pos = atomicAdd(&cursor[d], 1);
  csr_src[pos] = s;
}

// ---------------- XCD-pinned chunk-column aggregate + bf16 split -----------
template <int NCH, bool DUAL>
__global__ __launch_bounds__(256) void k_agg_x(
    const float* __restrict__ in0, const float* __restrict__ in1,
    unsigned short* __restrict__ Ah, unsigned short* __restrict__ Al,
    const int* __restrict__ row_ptr, const int* __restrict__ csr_src,
    const float* __restrict__ dinv) {
  constexpr int F4TOT = NCH * 8;
  const int bid = blockIdx.x;
  const int xcd = bid & 7;
  const int seq = bid >> 3;
  int chunk, nodeblk;
  if constexpr (NCH >= 8) {
    int phase = seq / NB2;
    nodeblk = seq - phase * NB2;
    chunk = phase * 8 + xcd;
  } else {  // NCH == 4: two XCDs share a chunk (even/odd node-blocks)
    chunk = xcd >> 1;
    nodeblk = (seq << 1) | (xcd & 1);
  }
  const int t = threadIdx.x;
  const int node = nodeblk * 32 + (t >> 3);
  const int f4 = chunk * 8 + (t & 7);

  size_t o = (size_t)node * F4TOT + f4;
  ushort4* oh = (ushort4*)Ah + o;
  ushort4* ol = (ushort4*)Al + o;
  int local = (node < NNP2) ? node : (node - NNP2);
  if (local >= NN) {   // pad row
    *oh = make_ushort4(0, 0, 0, 0);
    *ol = make_ushort4(0, 0, 0, 0);
    return;
  }
  const float4* i0 = (const float4*)in0;
  const float4* i1 = (const float4*)in1;
  auto rowp = [&](int g) -> const float4* {
    if (DUAL)
      return (g < NNP2) ? (i0 + (size_t)g * F4TOT)
                        : (i1 + (size_t)(g - NNP2) * F4TOT);
    return i0 + (size_t)g * F4TOT;
  };

  float di = dinv[node];
  float sw = di * di;
  float4 v = rowp(node)[f4];
  float4 acc;
  acc.x = sw * v.x; acc.y = sw * v.y; acc.z = sw * v.z; acc.w = sw * v.w;

  const int e0 = row_ptr[node], e1 = row_ptr[node + 1];
  int e = e0;
  for (; e + 4 <= e1; e += 4) {
    int s0 = csr_src[e], s1 = csr_src[e + 1];
    int s2 = csr_src[e + 2], s3 = csr_src[e + 3];
    float4 u0 = rowp(s0)[f4];
    float4 u1 = rowp(s1)[f4];
    float4 u2 = rowp(s2)[f4];
    float4 u3 = rowp(s3)[f4];
    float w0 = dinv[s0] * di, w1 = dinv[s1] * di;
    float w2 = dinv[s2] * di, w3 = dinv[s3] * di;
    fma4(acc, w0, u0);
    fma4(acc, w1, u1);
    fma4(acc, w2, u2);
    fma4(acc, w3, u3);
  }
  for (; e < e1; ++e) {
    int s = csr_src[e];
    float4 u = rowp(s)[f4];
    fma4(acc, dinv[s] * di, u);
  }

  ushort4 h, l;
  h.x = f2bf(acc.x); l.x = f2bf(acc.x - bf2f(h.x));
  h.y = f2bf(acc.y); l.y = f2bf(acc.y - bf2f(h.y));
  h.z = f2bf(acc.z); l.z = f2bf(acc.z - bf2f(h.z));
  h.w = f2bf(acc.w); l.w = f2bf(acc.w - bf2f(h.w));
  *oh = h;
  *ol = l;
}

// ---------------- weight transpose + split, 2 weight sets batched --------
__global__ __launch_bounds__(256) void k_wsplit2(
    const float* __restrict__ W0, unsigned short* __restrict__ H0,
    unsigned short* __restrict__ L0,
    const float* __restrict__ W1, unsigned short* __restrict__ H1,
    unsigned short* __restrict__ L1, int K, int N) {
  const float* W = blockIdx.z ? W1 : W0;
  unsigned short* Ht = blockIdx.z ? H1 : H0;
  unsigned short* Lt = blockIdx.z ? L1 : L0;
  __shared__ float tile[32][33];
  int nb = blockIdx.x * 32, kb = blockIdx.y * 32;
  int tx = threadIdx.x & 31, ty = threadIdx.x >> 5;
#pragma unroll
  for (int r = ty; r < 32; r += 8)
    tile[r][tx] = W[(size_t)(kb + r) * N + nb + tx];
  __syncthreads();
#pragma unroll
  for (int r = ty; r < 32; r += 8) {
    float x = tile[tx][r];  // = W[kb+tx][nb+r]
    unsigned short h = f2bf(x);
    unsigned short lo = f2bf(x - bf2f(h));
    size_t o = (size_t)(nb + r) * K + kb + tx;
    Ht[o] = h;
    Lt[o] = lo;
  }
}

// ---------------- split-bf16 MFMA GEMM 128x128 (R12 schedule) -------------
// bm-pinned XCD mapping: xcd=bid&7 owns bm rows {xcd, xcd+8, ...}; bn walks
// consecutively on the same XCD so the A panel stays L2-resident.
template <bool RELU, int GX, int LGX>
__global__ __launch_bounds__(256) void k_mgemm(
    const unsigned short* __restrict__ Ah, const unsigned short* __restrict__ Al,
    const unsigned short* __restrict__ Bh_a, const unsigned short* __restrict__ Bl_a,
    const unsigned short* __restrict__ Bh_b, const unsigned short* __restrict__ Bl_b,
    const float* __restrict__ bias_a, const float* __restrict__ bias_b,
    float* __restrict__ C, int N, int K) {
  __shared__ char smem[65536];  // 2 x [Ah|Al|Bh|Bl] x 8KiB
  const int t = threadIdx.x;
  const int w = t >> 6, l = t & 63;

  const int bid = blockIdx.x;
  const int bn_ = (bid >> 3) & (GX - 1);
  const int bm_ = (bid & 7) + ((bid >> (3 + LGX)) << 3);
  const int bm = bm_ * 128, bn = bn_ * 128;
  const bool sec = bm >= NNP2;
  const unsigned short* Bh = sec ? Bh_b : Bh_a;
  const unsigned short* Bl = sec ? Bl_b : Bl_a;
  const float* bias = sec ? bias_b : bias_a;

  const int wr = w >> 1, wc = w & 1;

  f32x4 acc[4][4] = {};

  // staging: wave w owns matrix w entirely (8 x 1KiB chunks)
  const unsigned short* g0 = (w == 0) ? Ah : (w == 1) ? Al : (w == 2) ? Bh : Bl;
  const int rb = (w < 2) ? bm : bn;
  const unsigned short* gbase = g0 + (size_t)(rb + (l & 15)) * K + ((l >> 4) * 8);
  const int sdoff = w * 8192 + l * 16;
  const int saoff = wr * 4096 + l * 16;          // A-hi frags; A-lo at +8192
  const int sboff = 16384 + wc * 4096 + l * 16;  // B-hi frags; B-lo at +8192

  const int nt = K >> 5;

#define STAGE(kt, b)                                                         \
  {                                                                          \
    const unsigned short* gk = gbase + ((kt) << 5);                          \
    char* sd = smem + (b)*32768 + sdoff;                                     \
    _Pragma("unroll") for (int s = 0; s < 8; ++s)                            \
        GLOAD_LDS16(gk + (size_t)s * 16 * K, sd + s * 1024);                 \
  }

  STAGE(0, 0)

  for (int kt = 0; kt < nt; ++kt) {
    const int cur = kt & 1;
    if (kt + 1 < nt) {
      STAGE(kt + 1, cur ^ 1)
      asm volatile("s_waitcnt vmcnt(8)" ::: "memory");  // tile kt landed
    } else {
      asm volatile("s_waitcnt vmcnt(0)" ::: "memory");
    }
    __builtin_amdgcn_sched_barrier(0);
    __builtin_amdgcn_s_barrier();  // collective: buf[cur] fully staged

    const char* sA = smem + cur * 32768 + saoff;
    const char* sB = smem + cur * 32768 + sboff;
    bf16x8 a[4][2], b[4][2];
#pragma unroll
    for (int i = 0; i < 4; ++i) {
      a[i][0] = *(const bf16x8*)(sA + i * 1024);
      a[i][1] = *(const bf16x8*)(sA + 8192 + i * 1024);
    }
#pragma unroll
    for (int j = 0; j < 4; ++j) {
      b[j][0] = *(const bf16x8*)(sB + j * 1024);
      b[j][1] = *(const bf16x8*)(sB + 8192 + j * 1024);
    }
    asm volatile("s_waitcnt lgkmcnt(0)" ::: "memory");  // frag reads done
    __builtin_amdgcn_sched_barrier(0);
    __builtin_amdgcn_s_barrier();  // all reads done; next STAGE may overwrite

    __builtin_amdgcn_s_setprio(1);
#pragma unroll
    for (int i = 0; i < 4; ++i)
#pragma unroll
      for (int j = 0; j < 4; ++j) {
        acc[i][j] = __builtin_amdgcn_mfma_f32_16x16x32_bf16(a[i][0], b[j][0], acc[i][j], 0, 0, 0);
        acc[i][j] = __builtin_amdgcn_mfma_f32_16x16x32_bf16(a[i][0], b[j][1], acc[i][j], 0, 0, 0);
        acc[i][j] = __builtin_amdgcn_mfma_f32_16x16x32_bf16(a[i][1], b[j][0], acc[i][j], 0, 0, 0);
      }
    __builtin_amdgcn_s_setprio(0);
  }
#undef STAGE

  // epilogue: C/D layout: col = lane&15, row = (lane>>4)*4 + reg
  const int r0 = bm + wr * 64 + ((l >> 4) << 2);
  const int c0 = bn + wc * 64 + (l & 15);
#pragma unroll
  for (int j = 0; j < 4; ++j) {
    const int col = c0 + j * 16;
    const float bv = bias[col];
#pragma unroll
    for (int i = 0; i < 4; ++i) {
      const int row = r0 + i * 16;
#pragma unroll
      for (int r = 0; r < 4; ++r) {
        float v = acc[i][j][r] + bv;
        if (RELU) v = fmaxf(v, 0.f);
        C[(size_t)(row + r) * N + col] = v;
      }
    }
  }
}

// ---------------- L3: 256x256 / 8-wave mgemm + fused bias/ReLU/max-pool ----
// (R12 schedule; bm-pinned XCD mapping: xcd owns bm-panels {xcd, xcd+8,...},
//  walks all 8 bn consecutively -> A panel L2-resident.)
__global__ __launch_bounds__(512, 2) void k_mgemm3(
    const unsigned short* __restrict__ Ah, const unsigned short* __restrict__ Al,
    const unsigned short* __restrict__ Bh_a, const unsigned short* __restrict__ Bl_a,
    const unsigned short* __restrict__ Bh_b, const unsigned short* __restrict__ Bl_b,
    const float* __restrict__ bias_a, const float* __restrict__ bias_b,
    const int* __restrict__ bs, const int* __restrict__ bt,
    float* __restrict__ P2, int N, int K) {
  __shared__ char smem[131072];
  const int t = threadIdx.x;
  const int w = t >> 6, l = t & 63;
  const int bid = blockIdx.x;
  const int bn_ = (bid >> 3) & 7;
  const int bm_ = (bid & 7) + ((bid >> 6) << 3);
  const int bm = bm_ * 256, bn = bn_ * 256;
  const bool sec = bm >= NNP2;            // 10240 % 256 == 0: no straddle
  const unsigned short* Bh = sec ? Bh_b : Bh_a;
  const unsigned short* Bl = sec ? Bl_b : Bl_a;
  const float* bias = sec ? bias_b : bias_a;
  const int* batch = sec ? bt : bs;
  float* P2g = P2 + (sec ? (size_t)NG * 2048 : 0);
  const int lbase = bm - (sec ? NNP2 : 0);  // branch-local row base

  const int wr = w >> 2, wc = w & 3;

  f32x4 acc[8][4] = {};

  // staging: part = w>>1 (0:Ahi 1:Alo 2:Bhi 3:Blo); half = w&1 (rows +0/+128)
  const int part = w >> 1, half = w & 1;
  const unsigned short* gmat = (part == 0) ? Ah : (part == 1) ? Al
                             : (part == 2) ? Bh : Bl;
  const int rb = ((part < 2) ? bm : bn) + half * 128;
  const unsigned short* gsbase = gmat + (size_t)(rb + (l & 15)) * K + ((l >> 4) * 8);
  const int sdoff = part * 16384 + half * 8192 + l * 16;

  const int saoff = (wr * 8) * 1024 + l * 16;          // A-hi; A-lo +16384
  const int sboff = 32768 + (wc * 4) * 1024 + l * 16;  // B-hi; B-lo +16384

  const int nt = K >> 5;

#define STAGE3(kt, b)                                                        \
  {                                                                          \
    _Pragma("unroll") for (int c = 0; c < 8; ++c)                            \
        GLOAD_LDS16(gsbase + (size_t)c * 16 * K + ((kt) << 5),               \
                    smem + (b)*65536 + sdoff + c * 1024);                    \
  }

  STAGE3(0, 0)

  for (int kt = 0; kt < nt; ++kt) {
    const int cur = kt & 1;
    if (kt + 1 < nt) {
      STAGE3(kt + 1, cur ^ 1)
      asm volatile("s_waitcnt vmcnt(8)" ::: "memory");
    } else {
      asm volatile("s_waitcnt vmcnt(0)" ::: "memory");
    }
    __builtin_amdgcn_sched_barrier(0);
    __builtin_amdgcn_s_barrier();

    const char* base = smem + cur * 65536;
    bf16x8 bh[4], blo[4], ah[8], alo[8];
#pragma unroll
    for (int j = 0; j < 4; ++j) {
      bh[j]  = *(const bf16x8*)(base + sboff + j * 1024);
      blo[j] = *(const bf16x8*)(base + sboff + 16384 + j * 1024);
    }
#pragma unroll
    for (int i = 0; i < 8; ++i) {
      ah[i]  = *(const bf16x8*)(base + saoff + i * 1024);
      alo[i] = *(const bf16x8*)(base + saoff + 16384 + i * 1024);
    }
    asm volatile("s_waitcnt lgkmcnt(0)" ::: "memory");
    __builtin_amdgcn_sched_barrier(0);
    __builtin_amdgcn_s_barrier();

    __builtin_amdgcn_s_setprio(1);
#pragma unroll
    for (int i = 0; i < 8; ++i)
#pragma unroll
      for (int j = 0; j < 4; ++j) {
        acc[i][j] = __builtin_amdgcn_mfma_f32_16x16x32_bf16(ah[i], bh[j], acc[i][j], 0, 0, 0);
        acc[i][j] = __builtin_amdgcn_mfma_f32_16x16x32_bf16(ah[i], blo[j], acc[i][j], 0, 0, 0);
        acc[i][j] = __builtin_amdgcn_mfma_f32_16x16x32_bf16(alo[i], bh[j], acc[i][j], 0, 0, 0);
      }
    __builtin_amdgcn_s_setprio(0);
  }
#undef STAGE3

  // epilogue: bias + ReLU + segmented atomicMax pool (no C store)
  const int r0l = lbase + wr * 128 + ((l >> 4) << 2);
  const int c0 = bn + wc * 64 + (l & 15);
#pragma unroll
  for (int j = 0; j < 4; ++j) {
    const int col = c0 + j * 16;
    const float bv = bias[col];
    float* Pcol = P2g + col;
#pragma unroll
    for (int i = 0; i < 8; ++i) {
      const int rl = r0l + i * 16;
      if (rl >= NN) continue;
      float v0 = fmaxf(acc[i][j][0] + bv, 0.f);
      float v1 = fmaxf(acc[i][j][1] + bv, 0.f);
      float v2 = fmaxf(acc[i][j][2] + bv, 0.f);
      float v3 = fmaxf(acc[i][j][3] + bv, 0.f);
      if (rl + 3 < NN) {
        int g0i = batch[rl], g3i = batch[rl + 3];
        if (g0i == g3i) {
          float m = fmaxf(fmaxf(v0, v1), fmaxf(v2, v3));
          atomicMax((int*)(Pcol + (size_t)g0i * 2048), __float_as_int(m));
        } else {
          int g1i = batch[rl + 1], g2i = batch[rl + 2];
          atomicMax((int*)(Pcol + (size_t)g0i * 2048), __float_as_int(v0));
          atomicMax((int*)(Pcol + (size_t)g1i * 2048), __float_as_int(v1));
          atomicMax((int*)(Pcol + (size_t)g2i * 2048), __float_as_int(v2));
          atomicMax((int*)(Pcol + (size_t)g3i * 2048), __float_as_int(v3));
        }
      } else {
        float vv[4] = {v0, v1, v2, v3};
        for (int r = 0; r < 4; ++r) {
          if (rl + r < NN) {
            int g = batch[rl + r];
            atomicMax((int*)(Pcol + (size_t)g * 2048), __float_as_int(vv[r]));
          }
        }
      }
    }
  }
}

// ---------------- split-K fp32 GEMM for the tiny head (M=128) -------------
__global__ __launch_bounds__(256) void k_gemm_sk(
    const float* __restrict__ A, const float* __restrict__ A2,
    const float* __restrict__ B,
    float* __restrict__ PART, int M, int N, int K, int KS) {
  __shared__ float As[32][64];
  __shared__ float Bs[32][64];

  int t = threadIdx.x;
  int tx = t & 15, ty = t >> 4;
  int bm = blockIdx.y * 64, bn = blockIdx.x * 64;
  int kbeg = blockIdx.z * KS, kend = kbeg + KS;

  float acc[4][4] = {};

  int arow0 = t >> 3;
  int ak4 = (t & 7) * 4;
  int brow0 = t >> 4;
  int bn4 = (t & 15) * 4;
  const bool n4al = (N & 3) == 0;

  for (int k0 = kbeg; k0 < kend; k0 += 32) {
#pragma unroll
    for (int c = 0; c < 2; ++c) {
      int row = arow0 + c * 32;
      int gr = bm + row;
      float4 v = make_float4(0.f, 0.f, 0.f, 0.f);
      if (gr < M) {
        v = *(const float4*)&A[(size_t)gr * K + k0 + ak4];
        if (A2) {
          float4 v2 = *(const float4*)&A2[(size_t)gr * K + k0 + ak4];
          v.x += v2.x; v.y += v2.y; v.z += v2.z; v.w += v2.w;
        }
      }
      As[ak4 + 0][row] = v.x;
      As[ak4 + 1][row] = v.y;
      As[ak4 + 2][row] = v.z;
      As[ak4 + 3][row] = v.w;
    }
#pragma unroll
    for (int c = 0; c < 2; ++c) {
      int row = brow0 + c * 16;
      int gc = bn + bn4;
      const float* bp = &B[(size_t)(k0 + row) * N + gc];
      float4 v;
      if (n4al && gc + 3 < N) {
        v = *(const float4*)bp;
      } else {
        v = make_float4(0.f, 0.f, 0.f, 0.f);
        if (gc < N) v.x = bp[0];
        if (gc + 1 < N) v.y = bp[1];
        if (gc + 2 < N) v.z = bp[2];
        if (gc + 3 < N) v.w = bp[3];
      }
      *(float4*)&Bs[row][bn4] = v;
    }
    __syncthreads();

#pragma unroll
    for (int kk = 0; kk < 32; ++kk) {
      float4 a = *(const float4*)&As[kk][ty * 4];
      float4 b = *(const float4*)&Bs[kk][tx * 4];
      float av[4] = {a.x, a.y, a.z, a.w};
      float bv[4] = {b.x, b.y, b.z, b.w};
#pragma unroll
      for (int i = 0; i < 4; ++i)
#pragma unroll
        for (int j = 0; j < 4; ++j)
          acc[i][j] = fmaf(av[i], bv[j], acc[i][j]);
    }
    __syncthreads();
  }

  float* P = PART + (size_t)blockIdx.z * M * N;
  int r0 = bm + ty * 4, c0 = bn + tx * 4;
#pragma unroll
  for (int i = 0; i < 4; ++i) {
    int r = r0 + i;
    if (r < M) {
#pragma unroll
      for (int j = 0; j < 4; ++j) {
        int c = c0 + j;
        if (c < N) P[(size_t)r * N + c] = acc[i][j];
      }
    }
  }
}

// reduce SK partials + bias (+relu or logits+sigmoid)
template <bool SIG>
__global__ void k_reduce(const float* __restrict__ PART,
                         const float* __restrict__ bias,
                         float* __restrict__ C, float* __restrict__ C2,
                         int MN, int N, int SK) {
  int i = blockIdx.x * blockDim.x + threadIdx.x;
  if (i >= MN) return;
  float s = 0.f;
  for (int z = 0; z < SK; ++z) s += PART[(size_t)z * MN + i];
  s += bias[i % N];
  if (SIG) {
    C[i] = s;
    C2[i] = 1.0f / (1.0f + __expf(-s));
  } else {
    C[i] = fmaxf(s, 0.f);
  }
}

// ---------------- entry ----------------

extern "C" void kernel_launch(void* const* d_in, const int* in_sizes, int n_in,
                              void* d_out, int out_size, void* d_ws, size_t ws_size,
                              hipStream_t stream) {
  const float* x_s = (const float*)d_in[0];
  const float* x_t = (const float*)d_in[1];
  const int* ei_s = (const int*)d_in[2];
  const int* ei_t = (const int*)d_in[3];
  const int* xs_batch = (const int*)d_in[4];
  const int* xt_batch = (const int*)d_in[5];
  const float* W_enc1 = (const float*)d_in[6];
  const float* b_enc1 = (const float*)d_in[7];
  const float* W_enc2 = (const float*)d_in[8];
  const float* b_enc2 = (const float*)d_in[9];
  const float* W_r1g1 = (const float*)d_in[10];
  const float* b_r1g1 = (const float*)d_in[11];
  const float* W_r1g2 = (const float*)d_in[12];
  const float* b_r1g2 = (const float*)d_in[13];
  const float* W_r2g1 = (const float*)d_in[14];
  const float* b_r2g1 = (const float*)d_in[15];
  const float* W_r2g2 = (const float*)d_in[16];
  const float* b_r2g2 = (const float*)d_in[17];
  const float* W_l1 = (const float*)d_in[18];
  const float* b_l1 = (const float*)d_in[19];
  const float* W_l2 = (const float*)d_in[20];
  const float* b_l2 = (const float*)d_in[21];

  float* out = (float*)d_out;

  char* ws = (char*)d_ws;
  size_t off = 0;
  auto carve = [&](size_t bytes) {
    char* p = ws + off;
    off = (off + bytes + 255) & ~(size_t)255;
    return p;
  };
  // ACT: L1 out (MT2 x 512 f32) then L2 out (MT2 x 1024 f32). L3 output is
  // never materialized (fused atomic pool).
  float* ACT = (float*)carve((size_t)MT2 * 1024 * 4);
  unsigned short* Ah = (unsigned short*)carve((size_t)MT2 * 1024 * 2);
  unsigned short* Al = (unsigned short*)carve((size_t)MT2 * 1024 * 2);
  // weight splits (transposed [N][K] bf16 hi/lo)
  unsigned short* W1h_a = (unsigned short*)carve((size_t)512 * 128 * 2);
  unsigned short* W1l_a = (unsigned short*)carve((size_t)512 * 128 * 2);
  unsigned short* W1h_b = (unsigned short*)carve((size_t)512 * 128 * 2);
  unsigned short* W1l_b = (unsigned short*)carve((size_t)512 * 128 * 2);
  unsigned short* W2h_a = (unsigned short*)carve((size_t)1024 * 512 * 2);
  unsigned short* W2l_a = (unsigned short*)carve((size_t)1024 * 512 * 2);
  unsigned short* W2h_b = (unsigned short*)carve((size_t)1024 * 512 * 2);
  unsigned short* W2l_b = (unsigned short*)carve((size_t)1024 * 512 * 2);
  unsigned short* W3h_a = (unsigned short*)carve((size_t)2048 * 1024 * 2);
  unsigned short* W3l_a = (unsigned short*)carve((size_t)2048 * 1024 * 2);
  unsigned short* W3h_b = (unsigned short*)carve((size_t)2048 * 1024 * 2);
  unsigned short* W3l_b = (unsigned short*)carve((size_t)2048 * 1024 * 2);
  float* P2   = (float*)carve((size_t)2 * NG * 2048 * 4);   // pooled, both branches
  float* ZZ   = (float*)carve((size_t)NG * 1024 * 4);
  float* PART = (float*)carve((size_t)16 * NG * 1024 * 4);  // split-K partials
  float* dinv = (float*)carve((size_t)MT2 * 4);
  int* cnt     = (int*)carve((size_t)MT2 * 4);
  int* row_ptr = (int*)carve((size_t)(MT2 + 1) * 4);
  int* cursor  = (int*)carve((size_t)MT2 * 4);
  int* csr_src = (int*)carve((size_t)2 * NE * 4);
  (void)ws_size; (void)n_in; (void)in_sizes; (void)out_size;

  // weight transpose+split, both branches batched via grid.z
  k_wsplit2<<<dim3(512 / 32, 128 / 32, 2), 256, 0, stream>>>(
      W_enc1, W1h_a, W1l_a, W_enc2, W1h_b, W1l_b, 128, 512);
  k_wsplit2<<<dim3(1024 / 32, 512 / 32, 2), 256, 0, stream>>>(
      W_r1g1, W2h_a, W2l_a, W_r2g1, W2h_b, W2l_b, 512, 1024);
  k_wsplit2<<<dim3(2048 / 32, 1024 / 32, 2), 256, 0, stream>>>(
      W_r1g2, W3h_a, W3l_a, W_r2g2, W3h_b, W3l_b, 1024, 2048);

  // batched CSR build
  hipMemsetAsync(cnt, 0, (size_t)MT2 * 4, stream);
  k_count2<<<(2 * NE + 255) / 256, 256, 0, stream>>>(ei_s, ei_t, cnt);
  k_scan<<<1, 256, 0, stream>>>(cnt, row_ptr, cursor, dinv);
  k_scatter2<<<(2 * NE + 255) / 256, 256, 0, stream>>>(ei_s, ei_t, cursor, csr_src);

  // L1: agg (dual input) [F=128] -> GEMM M=MT2, N=512, K=128 (no relu)
  k_agg_x<4, true><<<NB2 * 4, 256, 0, stream>>>(
      x_s, x_t, Ah, Al, row_ptr, csr_src, dinv);
  k_mgemm<false, 4, 2><<<4 * (MT2 / 128), 256, 0, stream>>>(
      Ah, Al, W1h_a, W1l_a, W1h_b, W1l_b, b_enc1, b_enc2, ACT, 512, 128);

  // L2: agg [F=512] -> relu GEMM M=MT2, N=1024, K=512
  k_agg_x<16, false><<<NB2 * 16, 256, 0, stream>>>(
      ACT, nullptr, Ah, Al, row_ptr, csr_src, dinv);
  k_mgemm<true, 8, 3><<<8 * (MT2 / 128), 256, 0, stream>>>(
      Ah, Al, W2h_a, W2l_a, W2h_b, W2l_b, b_r1g1, b_r2g1, ACT, 1024, 512);

  // L3: agg [F=1024] -> merged 256^2 GEMM with fused atomicMax pool
  k_agg_x<32, false><<<NB2 * 32, 256, 0, stream>>>(
      ACT, nullptr, Ah, Al, row_ptr, csr_src, dinv);
  hipMemsetAsync(P2, 0, (size_t)2 * NG * 2048 * 4, stream);
  k_mgemm3<<<8 * (MT2 / 256), 512, 0, stream>>>(
      Ah, Al, W3h_a, W3l_a, W3h_b, W3l_b, b_r1g2, b_r2g2,
      xs_batch, xt_batch, P2, 2048, 1024);

  // MLP head, split-K fp32 (Z = P_s + P_t fused into A-load)
  k_gemm_sk<<<dim3(1024 / 64, 2, 16), 256, 0, stream>>>(
      P2, P2 + (size_t)NG * 2048, W_l1, PART, NG, 1024, 2048, 128);
  k_reduce<false><<<(NG * 1024 + 255) / 256, 256, 0, stream>>>(
      PART, b_l1, ZZ, nullptr, NG * 1024, 1024, 16);

  const int OUTN = 1317;
  k_gemm_sk<<<dim3((OUTN + 63) / 64, 2, 8), 256, 0, stream>>>(
      ZZ, nullptr, W_l2, PART, NG, OUTN, 1024, 128);
  k_reduce<true><<<(NG * OUTN + 255) / 256, 256, 0, stream>>>(
      PART, b_l2, out, out + (size_t)NG * OUTN, NG * OUTN, OUTN, 8);
}